// Round 8
// baseline (324.983 us; speedup 1.0000x reference)
//
#include <hip/hip_runtime.h>
#include <hip/hip_bf16.h>
#include <math.h>

// B=2, N=2048, M=1024, H=16, DK=64. fp32 in/out.
// R8 = R7 + per-mode precision terms:
//   Q proj:   (xh+xl)*wh   2-term   (q feeds QK; needs fp32-grade)
//   K,V proj:  xh*wh       1-term   (delta ~2^-9 rel, damped downstream)
//   QK:       (qh+ql)*kh   2-term
//   PV:        ph*vh       1-term
//   out proj: (ch+cl)*wh   2-term
// 1/8 attention scale folded into Wq/bq at split time (saves 16 VALU/iter).

typedef __attribute__((ext_vector_type(8))) short bf16x8;
typedef __attribute__((ext_vector_type(4))) float f32x4;

__device__ __forceinline__ short f2b(float f) {
    union { __hip_bfloat16 h; short s; } u;
    u.h = __float2bfloat16(f);   // RNE
    return u.s;
}
__device__ __forceinline__ float b2f(short s) {
    union { short s; __hip_bfloat16 h; } u;
    u.s = s;
    return __bfloat162float(u.h);
}

// XOR-swizzled element offset inside a [rows][64]-bf16 tile (16B blocks).
__device__ __forceinline__ int sw8(int r, int k8) {       // k8 = octet 0..7
    return (r << 6) + ((k8 ^ (r & 7)) << 3);
}
__device__ __forceinline__ int swe(int r, int k) {        // element-level
    return (r << 6) + (((k >> 3) ^ (r & 7)) << 3) + (k & 7);
}

// workspace layout (SHORT offsets). Every plane = 4194304 shorts (8 MB).
#define PLANE   4194304UL
#define OFF_WH  (0UL * PLANE)    // [4][1024][1024] W hi (Wq|Wk|Wv|Wo); Wq pre-scaled by 1/8
#define OFF_XH  (1UL * PLANE)    // [4096][1024] x hi
#define OFF_XL  (2UL * PLANE)    // x lo
#define OFF_QH  (3UL * PLANE)    // [B,H,N,DK]
#define OFF_QL  (4UL * PLANE)
#define OFF_KH  (5UL * PLANE)    // hi only
#define OFF_VTH (6UL * PLANE)    // [B,H,DK,N] hi only
#define OFF_CH  (7UL * PLANE)    // [B,N,M] concat hi
#define OFF_CL  (8UL * PLANE)    // concat lo

// ---------------------------------------------------------------------------
// Pre-split: W -> hi only (Wq scaled by 1/8); x -> hi + lo.
// ---------------------------------------------------------------------------
__global__ __launch_bounds__(256) void split_wx(
    const float* __restrict__ Wq, const float* __restrict__ Wk,
    const float* __restrict__ Wv, const float* __restrict__ Wo,
    const float* __restrict__ x,
    unsigned short* __restrict__ wh,
    unsigned short* __restrict__ xh, unsigned short* __restrict__ xl)
{
    const int i = blockIdx.x * 256 + threadIdx.x;   // float4 idx, 2097152 total
    if (i < 1048576) {                               // weights: hi only
        const float* src = (i < 262144) ? Wq : (i < 524288) ? Wk
                         : (i < 786432) ? Wv : Wo;
        const float sc = (i < 262144) ? 0.125f : 1.0f;   // fold attention scale
        const int local = i & 262143;
        float4 v = ((const float4*)src)[local];
        short4 h;
        h.x = f2b(v.x * sc); h.y = f2b(v.y * sc);
        h.z = f2b(v.z * sc); h.w = f2b(v.w * sc);
        ((short4*)(wh + (size_t)(i >> 18) * 1048576))[local] = h;
    } else {                                         // x: hi + lo
        const int local = i - 1048576;
        float4 v = ((const float4*)x)[local];
        short4 h, l;
        h.x = f2b(v.x); l.x = f2b(v.x - b2f(h.x));
        h.y = f2b(v.y); l.y = f2b(v.y - b2f(h.y));
        h.z = f2b(v.z); l.z = f2b(v.z - b2f(h.z));
        h.w = f2b(v.w); l.w = f2b(v.w - b2f(h.w));
        ((short4*)xh)[local] = h;
        ((short4*)xl)[local] = l;
    }
}

// ---------------------------------------------------------------------------
// Split GEMM: C = A @ W^T + bias, W hi-plane only.
// mode 0: Q (2-term A, hi+lo out, bias*1/8), 1: K (1-term, hi out),
// 2: V^T (1-term, hi out), 3: fp32 out (2-term A) + bias.
// 128x128 tile, 256 thr (4 waves 2x2), 4x4 16x16x32 frags, BK=64.
// ---------------------------------------------------------------------------
__global__ __launch_bounds__(256, 3) void gemm_split(
    const unsigned short* __restrict__ Ah, const unsigned short* __restrict__ Al,
    unsigned short* __restrict__ wsS,
    const float* __restrict__ b0, const float* __restrict__ b1,
    const float* __restrict__ b2, const float* __restrict__ b3,
    float* __restrict__ oout, int modeBase)
{
    __shared__ unsigned short Ash[128 * 64], Asl[128 * 64];
    __shared__ unsigned short Bsh[128 * 64];

    const int mode = modeBase + blockIdx.z;
    const bool terms2 = (mode == 0) || (mode == 3);   // uniform per block
    const unsigned short* Wh = wsS + OFF_WH + (size_t)mode * 1048576;
    const float* bias = (mode == 0) ? b0 : (mode == 1) ? b1 : (mode == 2) ? b2 : b3;
    const float bscale = (mode == 0) ? 0.125f : 1.0f;

    const int tid  = threadIdx.x;
    const int lane = tid & 63;
    const int lm   = lane & 15;
    const int quad = lane >> 4;
    const int w    = tid >> 6;
    const int wr   = w >> 1, wc = w & 1;

    const int row0 = blockIdx.y * 128;
    const int col0 = blockIdx.x * 128;

    const int sk8 = tid & 7;      // staging octet
    const int sr0 = tid >> 3;     // staging row 0..31

    f32x4 acc[4][4] = {};

    for (int k0 = 0; k0 < 1024; k0 += 64) {
        if (k0) __syncthreads();
        #pragma unroll
        for (int i = 0; i < 4; ++i) {
            const int r = sr0 + 32 * i;
            *(bf16x8*)&Ash[sw8(r, sk8)] =
                *(const bf16x8*)&Ah[(size_t)(row0 + r) * 1024 + k0 + sk8 * 8];
            if (terms2)
                *(bf16x8*)&Asl[sw8(r, sk8)] =
                    *(const bf16x8*)&Al[(size_t)(row0 + r) * 1024 + k0 + sk8 * 8];
            *(bf16x8*)&Bsh[sw8(r, sk8)] =
                *(const bf16x8*)&Wh[(size_t)(col0 + r) * 1024 + k0 + sk8 * 8];
        }
        __syncthreads();
        #pragma unroll
        for (int ks = 0; ks < 2; ++ks) {
            bf16x8 afh[4], bfh[4];
            #pragma unroll
            for (int mi = 0; mi < 4; ++mi)
                afh[mi] = *(const bf16x8*)&Ash[sw8(wr * 64 + mi * 16 + lm, ks * 4 + quad)];
            #pragma unroll
            for (int ni = 0; ni < 4; ++ni)
                bfh[ni] = *(const bf16x8*)&Bsh[sw8(wc * 64 + ni * 16 + lm, ks * 4 + quad)];
            #pragma unroll
            for (int mi = 0; mi < 4; ++mi) {
                #pragma unroll
                for (int ni = 0; ni < 4; ++ni)
                    acc[mi][ni] = __builtin_amdgcn_mfma_f32_16x16x32_bf16(
                        afh[mi], bfh[ni], acc[mi][ni], 0, 0, 0);
            }
            if (terms2) {
                bf16x8 afl[4];
                #pragma unroll
                for (int mi = 0; mi < 4; ++mi)
                    afl[mi] = *(const bf16x8*)&Asl[sw8(wr * 64 + mi * 16 + lm, ks * 4 + quad)];
                #pragma unroll
                for (int mi = 0; mi < 4; ++mi) {
                    #pragma unroll
                    for (int ni = 0; ni < 4; ++ni)
                        acc[mi][ni] = __builtin_amdgcn_mfma_f32_16x16x32_bf16(
                            afl[mi], bfh[ni], acc[mi][ni], 0, 0, 0);
                }
            }
        }
    }

    unsigned short* qh  = wsS + OFF_QH;
    unsigned short* ql  = wsS + OFF_QL;
    unsigned short* kh  = wsS + OFF_KH;
    unsigned short* vth = wsS + OFF_VTH;

    // epilogue: C/D layout col=lane&15, row=quad*4+reg
    #pragma unroll
    for (int ni = 0; ni < 4; ++ni) {
        const int f = col0 + wc * 64 + ni * 16 + lm;
        const float bv = bias[f] * bscale;
        const int h = f >> 6, d = f & 63;
        #pragma unroll
        for (int mi = 0; mi < 4; ++mi) {
            #pragma unroll
            for (int j = 0; j < 4; ++j) {
                const int row = row0 + wr * 64 + mi * 16 + quad * 4 + j;
                const float val = acc[mi][ni][j] + bv;
                if (mode == 3) {
                    oout[(size_t)row * 1024 + f] = val;
                } else {
                    const int bb = row >> 11, n = row & 2047;
                    const short hs = f2b(val);
                    if (mode == 2) {
                        vth[((size_t)(bb * 16 + h) * 64 + d) * 2048 + n] = hs;
                    } else {
                        const size_t idx = ((size_t)(bb * 16 + h) * 2048 + n) * 64 + d;
                        if (mode == 0) { qh[idx] = hs; ql[idx] = f2b(val - b2f(hs)); }
                        else           { kh[idx] = hs; }
                    }
                }
            }
        }
    }
}

// ---------------------------------------------------------------------------
// Flash attention (64-row blocks), deferred softmax normalization.
// QK 2-term (q-split x K-hi), PV 1-term (P-hi x V-hi). LDS 24KB, 4 blk/CU.
// Scale pre-folded into q -> p = exp(s * mask) directly.
// ---------------------------------------------------------------------------
__global__ __launch_bounds__(256, 4) void attn_fast(
    const unsigned short* __restrict__ wsS, const float* __restrict__ mask,
    unsigned short* __restrict__ ch, unsigned short* __restrict__ cl)
{
    __shared__ unsigned short Ksh[64 * 64];      // [kcol][d] hi
    __shared__ unsigned short Vth[64 * 64];      // [d][k]    hi
    __shared__ unsigned short Psh[4][16 * 64];   // per-wave [q][k] hi

    const int tid  = threadIdx.x;
    const int lane = tid & 63;
    const int lm   = lane & 15;
    const int quad = lane >> 4;
    const int w    = tid >> 6;

    const int q0 = blockIdx.x * 64;
    const int h  = blockIdx.y;
    const int b  = blockIdx.z;
    const int bh = b * 16 + h;

    const unsigned short* Qhg = wsS + OFF_QH  + (size_t)bh * 2048 * 64;
    const unsigned short* Qlg = wsS + OFF_QL  + (size_t)bh * 2048 * 64;
    const unsigned short* Khg = wsS + OFF_KH  + (size_t)bh * 2048 * 64;
    const unsigned short* Vhg = wsS + OFF_VTH + (size_t)bh * 64 * 2048;
    const float* Mg = mask + (size_t)b * 2048 * 2048;

    // Q frags in registers (this wave's 16 q-rows)
    bf16x8 qfh[2], qfl[2];
    #pragma unroll
    for (int ks = 0; ks < 2; ++ks) {
        const size_t qo = (size_t)(q0 + w * 16 + lm) * 64 + ks * 32 + quad * 8;
        qfh[ks] = *(const bf16x8*)&Qhg[qo];
        qfl[ks] = *(const bf16x8*)&Qlg[qo];
    }

    const int sk8 = tid & 7;
    const int sr0 = tid >> 3;   // 0..31

    // K/V staging registers (double-buffer), hi planes only
    bf16x8 rkh[2], rvh[2];
    #pragma unroll
    for (int i = 0; i < 2; ++i) {            // preload tile 0
        const int r = sr0 + 32 * i;
        rkh[i] = *(const bf16x8*)&Khg[(size_t)r * 64 + sk8 * 8];
        rvh[i] = *(const bf16x8*)&Vhg[(size_t)r * 2048 + sk8 * 8];
    }

    f32x4 o[4] = {};
    float lsum[4] = {0.f, 0.f, 0.f, 0.f};
    const int qwbase = q0 + w * 16 + quad * 4;

    for (int k0 = 0; k0 < 2048; k0 += 64) {
        // mask prefetch for THIS tile
        float mreg[4][4];
        #pragma unroll
        for (int j = 0; j < 4; ++j)
            #pragma unroll
            for (int ni = 0; ni < 4; ++ni)
                mreg[j][ni] = Mg[(size_t)(qwbase + j) * 2048 + k0 + ni * 16 + lm];

        __syncthreads();                      // prev iter's K/V frag reads done
        #pragma unroll
        for (int i = 0; i < 2; ++i) {
            const int r = sr0 + 32 * i;
            *(bf16x8*)&Ksh[sw8(r, sk8)] = rkh[i];
            *(bf16x8*)&Vth[sw8(r, sk8)] = rvh[i];
        }
        if (k0 + 64 < 2048) {                 // issue NEXT tile's global loads
            #pragma unroll
            for (int i = 0; i < 2; ++i) {
                const int r = sr0 + 32 * i;
                rkh[i] = *(const bf16x8*)&Khg[(size_t)(k0 + 64 + r) * 64 + sk8 * 8];
                rvh[i] = *(const bf16x8*)&Vhg[(size_t)r * 2048 + k0 + 64 + sk8 * 8];
            }
        }
        __syncthreads();

        // S ~= (qh+ql) K_hi^T : 2 MFMA per (ks,ni); scale pre-folded in q
        f32x4 s[4] = {};
        #pragma unroll
        for (int ks = 0; ks < 2; ++ks) {
            #pragma unroll
            for (int ni = 0; ni < 4; ++ni) {
                bf16x8 kh = *(const bf16x8*)&Ksh[sw8(ni * 16 + lm, ks * 4 + quad)];
                s[ni] = __builtin_amdgcn_mfma_f32_16x16x32_bf16(qfh[ks], kh, s[ni], 0, 0, 0);
                s[ni] = __builtin_amdgcn_mfma_f32_16x16x32_bf16(qfl[ks], kh, s[ni], 0, 0, 0);
            }
        }

        // p = exp(s * mask); per-lane partial row-sums; P(hi) -> LDS
        #pragma unroll
        for (int j = 0; j < 4; ++j) {
            #pragma unroll
            for (int ni = 0; ni < 4; ++ni) {
                const float p = __expf(s[ni][j] * mreg[j][ni]);
                lsum[j] += p;
                Psh[w][swe(quad * 4 + j, ni * 16 + lm)] = f2b(p);
            }
        }

        // O += P_hi @ V_hi : 1 MFMA per (ks,ni); own-wave LDS, no barrier
        #pragma unroll
        for (int ks = 0; ks < 2; ++ks) {
            bf16x8 ph = *(const bf16x8*)&Psh[w][sw8(lm, ks * 4 + quad)];
            #pragma unroll
            for (int ni = 0; ni < 4; ++ni) {
                bf16x8 vh = *(const bf16x8*)&Vth[sw8(ni * 16 + lm, ks * 4 + quad)];
                o[ni] = __builtin_amdgcn_mfma_f32_16x16x32_bf16(ph, vh, o[ni], 0, 0, 0);
            }
        }
    }

    // epilogue: one cross-lane row-sum reduction, normalize, split-store concat
    #pragma unroll
    for (int j = 0; j < 4; ++j) {
        float ls = lsum[j];
        ls += __shfl_xor(ls, 1);
        ls += __shfl_xor(ls, 2);
        ls += __shfl_xor(ls, 4);
        ls += __shfl_xor(ls, 8);
        const float inv = 1.0f / ls;
        const int q = qwbase + j;
        #pragma unroll
        for (int ni = 0; ni < 4; ++ni) {
            const float val = o[ni][j] * inv;
            const size_t idx = ((size_t)b * 2048 + q) * 1024 + h * 64 + ni * 16 + lm;
            const short hs = f2b(val);
            ch[idx] = hs;
            cl[idx] = f2b(val - b2f(hs));
        }
    }
}

extern "C" void kernel_launch(void* const* d_in, const int* in_sizes, int n_in,
                              void* d_out, int out_size, void* d_ws, size_t ws_size,
                              hipStream_t stream) {
    const float* x    = (const float*)d_in[0];
    const float* mask = (const float*)d_in[1];
    const float* Wq   = (const float*)d_in[2];
    const float* bq   = (const float*)d_in[3];
    const float* Wk   = (const float*)d_in[4];
    const float* bk   = (const float*)d_in[5];
    const float* Wv   = (const float*)d_in[6];
    const float* bv   = (const float*)d_in[7];
    const float* Wo   = (const float*)d_in[8];
    const float* bo   = (const float*)d_in[9];

    unsigned short* wsS = (unsigned short*)d_ws;

    // 1. pre-split: W -> hi (Wq/8); x -> hi+lo
    split_wx<<<8192, 256, 0, stream>>>(Wq, Wk, Wv, Wo, x,
        wsS + OFF_WH, wsS + OFF_XH, wsS + OFF_XL);

    // 2. Q/K/V projections (Q 2-term, K/V 1-term)
    gemm_split<<<dim3(8, 32, 3), 256, 0, stream>>>(
        wsS + OFF_XH, wsS + OFF_XL, wsS, bq, bk, bv, bo, nullptr, 0);

    // 3. fused masked-softmax flash attention (QK 2-term, PV 1-term)
    attn_fast<<<dim3(32, 16, 2), 256, 0, stream>>>(
        wsS, mask, wsS + OFF_CH, wsS + OFF_CL);

    // 4. output projection (2-term)
    gemm_split<<<dim3(8, 32, 1), 256, 0, stream>>>(
        wsS + OFF_CH, wsS + OFF_CL, wsS, bq, bk, bv, bo, (float*)d_out, 3);
}

// Round 9
// 297.918 us; speedup vs baseline: 1.0908x; 1.0908x over previous
//
#include <hip/hip_runtime.h>
#include <hip/hip_bf16.h>
#include <math.h>

// B=2, N=2048, M=1024, H=16, DK=64. fp32 in/out.
// R9: specialized GEMM kernels (no runtime branch in hot loops) +
// attn K/V LDS double-buffer with ONE barrier per K-tile.
// Precision plan (absmax ~9.8e-4 vs 3.96e-3 threshold):
//   Q proj:   (xh+xl)*wh   2-term      K,V proj:  xh*wh   1-term
//   QK:       (qh+ql)*kh   2-term      PV:        ph*vh   1-term
//   out proj: (ch+cl)*wh   2-term
// 1/8 attention scale folded into Wq/bq at split time.

typedef __attribute__((ext_vector_type(8))) short bf16x8;
typedef __attribute__((ext_vector_type(4))) float f32x4;

__device__ __forceinline__ short f2b(float f) {
    union { __hip_bfloat16 h; short s; } u;
    u.h = __float2bfloat16(f);   // RNE
    return u.s;
}
__device__ __forceinline__ float b2f(short s) {
    union { short s; __hip_bfloat16 h; } u;
    u.s = s;
    return __bfloat162float(u.h);
}

// XOR-swizzled element offset inside a [rows][64]-bf16 tile (16B blocks).
__device__ __forceinline__ int sw8(int r, int k8) {       // k8 = octet 0..7
    return (r << 6) + ((k8 ^ (r & 7)) << 3);
}
__device__ __forceinline__ int swe(int r, int k) {        // element-level
    return (r << 6) + (((k >> 3) ^ (r & 7)) << 3) + (k & 7);
}

// workspace layout (SHORT offsets). Every plane = 4194304 shorts (8 MB).
#define PLANE   4194304UL
#define OFF_WH  (0UL * PLANE)    // [4][1024][1024] W hi (Wq|Wk|Wv|Wo); Wq pre-scaled 1/8
#define OFF_XH  (1UL * PLANE)    // [4096][1024] x hi
#define OFF_XL  (2UL * PLANE)    // x lo
#define OFF_QH  (3UL * PLANE)    // [B,H,N,DK]
#define OFF_QL  (4UL * PLANE)
#define OFF_KH  (5UL * PLANE)    // hi only
#define OFF_VTH (6UL * PLANE)    // [B,H,DK,N] hi only
#define OFF_CH  (7UL * PLANE)    // [B,N,M] concat hi
#define OFF_CL  (8UL * PLANE)    // concat lo

// ---------------------------------------------------------------------------
// Pre-split: W -> hi only (Wq scaled by 1/8); x -> hi + lo.
// ---------------------------------------------------------------------------
__global__ __launch_bounds__(256) void split_wx(
    const float* __restrict__ Wq, const float* __restrict__ Wk,
    const float* __restrict__ Wv, const float* __restrict__ Wo,
    const float* __restrict__ x,
    unsigned short* __restrict__ wh,
    unsigned short* __restrict__ xh, unsigned short* __restrict__ xl)
{
    const int i = blockIdx.x * 256 + threadIdx.x;   // float4 idx, 2097152 total
    if (i < 1048576) {                               // weights: hi only
        const float* src = (i < 262144) ? Wq : (i < 524288) ? Wk
                         : (i < 786432) ? Wv : Wo;
        const float sc = (i < 262144) ? 0.125f : 1.0f;   // fold attention scale
        const int local = i & 262143;
        float4 v = ((const float4*)src)[local];
        short4 h;
        h.x = f2b(v.x * sc); h.y = f2b(v.y * sc);
        h.z = f2b(v.z * sc); h.w = f2b(v.w * sc);
        ((short4*)(wh + (size_t)(i >> 18) * 1048576))[local] = h;
    } else {                                         // x: hi + lo
        const int local = i - 1048576;
        float4 v = ((const float4*)x)[local];
        short4 h, l;
        h.x = f2b(v.x); l.x = f2b(v.x - b2f(h.x));
        h.y = f2b(v.y); l.y = f2b(v.y - b2f(h.y));
        h.z = f2b(v.z); l.z = f2b(v.z - b2f(h.z));
        h.w = f2b(v.w); l.w = f2b(v.w - b2f(h.w));
        ((short4*)xh)[local] = h;
        ((short4*)xl)[local] = l;
    }
}

// ---------------------------------------------------------------------------
// 2-term GEMM (R7's proven loop): C = (Ah+Al) @ Wh^T + bias.
// mode 0: Q -> hi/lo planes (bias*1/8); mode 3: fp32 out + bias.
// 128x128 tile, 4 waves 2x2, 4x4 frags, BK=64, LDS 48KB, 3 blocks/CU.
// ---------------------------------------------------------------------------
__global__ __launch_bounds__(256, 3) void gemm_2t(
    const unsigned short* __restrict__ Ah, const unsigned short* __restrict__ Al,
    unsigned short* __restrict__ wsS,
    const float* __restrict__ bias_p, float* __restrict__ oout, int mode)
{
    __shared__ unsigned short Ash[128 * 64], Asl[128 * 64];
    __shared__ unsigned short Bsh[128 * 64];

    const unsigned short* Wh = wsS + OFF_WH + (size_t)mode * 1048576;
    const float bscale = (mode == 0) ? 0.125f : 1.0f;

    const int tid  = threadIdx.x;
    const int lane = tid & 63;
    const int lm   = lane & 15;
    const int quad = lane >> 4;
    const int w    = tid >> 6;
    const int wr   = w >> 1, wc = w & 1;

    const int row0 = blockIdx.y * 128;
    const int col0 = blockIdx.x * 128;

    const int sk8 = tid & 7;
    const int sr0 = tid >> 3;

    f32x4 acc[4][4] = {};

    for (int k0 = 0; k0 < 1024; k0 += 64) {
        if (k0) __syncthreads();
        #pragma unroll
        for (int i = 0; i < 4; ++i) {
            const int r = sr0 + 32 * i;
            *(bf16x8*)&Ash[sw8(r, sk8)] =
                *(const bf16x8*)&Ah[(size_t)(row0 + r) * 1024 + k0 + sk8 * 8];
            *(bf16x8*)&Asl[sw8(r, sk8)] =
                *(const bf16x8*)&Al[(size_t)(row0 + r) * 1024 + k0 + sk8 * 8];
            *(bf16x8*)&Bsh[sw8(r, sk8)] =
                *(const bf16x8*)&Wh[(size_t)(col0 + r) * 1024 + k0 + sk8 * 8];
        }
        __syncthreads();
        #pragma unroll
        for (int ks = 0; ks < 2; ++ks) {
            bf16x8 afh[4], afl[4], bfh[4];
            #pragma unroll
            for (int mi = 0; mi < 4; ++mi) {
                afh[mi] = *(const bf16x8*)&Ash[sw8(wr * 64 + mi * 16 + lm, ks * 4 + quad)];
                afl[mi] = *(const bf16x8*)&Asl[sw8(wr * 64 + mi * 16 + lm, ks * 4 + quad)];
            }
            #pragma unroll
            for (int ni = 0; ni < 4; ++ni)
                bfh[ni] = *(const bf16x8*)&Bsh[sw8(wc * 64 + ni * 16 + lm, ks * 4 + quad)];
            #pragma unroll
            for (int mi = 0; mi < 4; ++mi) {
                #pragma unroll
                for (int ni = 0; ni < 4; ++ni) {
                    acc[mi][ni] = __builtin_amdgcn_mfma_f32_16x16x32_bf16(
                        afh[mi], bfh[ni], acc[mi][ni], 0, 0, 0);
                    acc[mi][ni] = __builtin_amdgcn_mfma_f32_16x16x32_bf16(
                        afl[mi], bfh[ni], acc[mi][ni], 0, 0, 0);
                }
            }
        }
    }

    unsigned short* qh = wsS + OFF_QH;
    unsigned short* ql = wsS + OFF_QL;

    #pragma unroll
    for (int ni = 0; ni < 4; ++ni) {
        const int f = col0 + wc * 64 + ni * 16 + lm;
        const float bv = bias_p[f] * bscale;
        const int h = f >> 6, d = f & 63;
        #pragma unroll
        for (int mi = 0; mi < 4; ++mi) {
            #pragma unroll
            for (int j = 0; j < 4; ++j) {
                const int row = row0 + wr * 64 + mi * 16 + quad * 4 + j;
                const float val = acc[mi][ni][j] + bv;
                if (mode == 3) {
                    oout[(size_t)row * 1024 + f] = val;
                } else {
                    const int bb = row >> 11, n = row & 2047;
                    const size_t idx = ((size_t)(bb * 16 + h) * 2048 + n) * 64 + d;
                    const short hs = f2b(val);
                    qh[idx] = hs;
                    ql[idx] = f2b(val - b2f(hs));
                }
            }
        }
    }
}

// ---------------------------------------------------------------------------
// 1-term GEMM: C = Ah @ Wh^T + bias. z selects K (mode 1) / V (mode 2).
// LDS 32KB -> 4 blocks/CU.
// ---------------------------------------------------------------------------
__global__ __launch_bounds__(256, 4) void gemm_1t(
    const unsigned short* __restrict__ Ah,
    unsigned short* __restrict__ wsS,
    const float* __restrict__ b1, const float* __restrict__ b2)
{
    __shared__ unsigned short Ash[128 * 64];
    __shared__ unsigned short Bsh[128 * 64];

    const int mode = 1 + blockIdx.z;
    const unsigned short* Wh = wsS + OFF_WH + (size_t)mode * 1048576;
    const float* bias = (mode == 1) ? b1 : b2;

    const int tid  = threadIdx.x;
    const int lane = tid & 63;
    const int lm   = lane & 15;
    const int quad = lane >> 4;
    const int w    = tid >> 6;
    const int wr   = w >> 1, wc = w & 1;

    const int row0 = blockIdx.y * 128;
    const int col0 = blockIdx.x * 128;

    const int sk8 = tid & 7;
    const int sr0 = tid >> 3;

    f32x4 acc[4][4] = {};

    for (int k0 = 0; k0 < 1024; k0 += 64) {
        if (k0) __syncthreads();
        #pragma unroll
        for (int i = 0; i < 4; ++i) {
            const int r = sr0 + 32 * i;
            *(bf16x8*)&Ash[sw8(r, sk8)] =
                *(const bf16x8*)&Ah[(size_t)(row0 + r) * 1024 + k0 + sk8 * 8];
            *(bf16x8*)&Bsh[sw8(r, sk8)] =
                *(const bf16x8*)&Wh[(size_t)(col0 + r) * 1024 + k0 + sk8 * 8];
        }
        __syncthreads();
        #pragma unroll
        for (int ks = 0; ks < 2; ++ks) {
            bf16x8 afh[4], bfh[4];
            #pragma unroll
            for (int mi = 0; mi < 4; ++mi)
                afh[mi] = *(const bf16x8*)&Ash[sw8(wr * 64 + mi * 16 + lm, ks * 4 + quad)];
            #pragma unroll
            for (int ni = 0; ni < 4; ++ni)
                bfh[ni] = *(const bf16x8*)&Bsh[sw8(wc * 64 + ni * 16 + lm, ks * 4 + quad)];
            #pragma unroll
            for (int mi = 0; mi < 4; ++mi) {
                #pragma unroll
                for (int ni = 0; ni < 4; ++ni)
                    acc[mi][ni] = __builtin_amdgcn_mfma_f32_16x16x32_bf16(
                        afh[mi], bfh[ni], acc[mi][ni], 0, 0, 0);
            }
        }
    }

    unsigned short* kh  = wsS + OFF_KH;
    unsigned short* vth = wsS + OFF_VTH;

    #pragma unroll
    for (int ni = 0; ni < 4; ++ni) {
        const int f = col0 + wc * 64 + ni * 16 + lm;
        const float bv = bias[f];
        const int h = f >> 6, d = f & 63;
        #pragma unroll
        for (int mi = 0; mi < 4; ++mi) {
            #pragma unroll
            for (int j = 0; j < 4; ++j) {
                const int row = row0 + wr * 64 + mi * 16 + quad * 4 + j;
                const float val = acc[mi][ni][j] + bv;
                const int bb = row >> 11, n = row & 2047;
                const short hs = f2b(val);
                if (mode == 2)
                    vth[((size_t)(bb * 16 + h) * 64 + d) * 2048 + n] = hs;
                else
                    kh[((size_t)(bb * 16 + h) * 2048 + n) * 64 + d] = hs;
            }
        }
    }
}

// ---------------------------------------------------------------------------
// Flash attention, deferred softmax normalization, K/V LDS DOUBLE-BUFFER:
// one barrier per K-tile. buf[t&1] written at iter-t top; its previous
// readers (compute t-2) are ordered by barrier(t-1) -> single barrier safe.
// QK 2-term, PV 1-term. LDS 40KB -> exactly 4 blocks/CU.
// ---------------------------------------------------------------------------
__global__ __launch_bounds__(256, 4) void attn_fast(
    const unsigned short* __restrict__ wsS, const float* __restrict__ mask,
    unsigned short* __restrict__ ch, unsigned short* __restrict__ cl)
{
    __shared__ unsigned short Ksh[2][64 * 64];   // [buf][kcol][d] hi
    __shared__ unsigned short Vth[2][64 * 64];   // [buf][d][k]    hi
    __shared__ unsigned short Psh[4][16 * 64];   // per-wave [q][k] hi

    const int tid  = threadIdx.x;
    const int lane = tid & 63;
    const int lm   = lane & 15;
    const int quad = lane >> 4;
    const int w    = tid >> 6;

    const int q0 = blockIdx.x * 64;
    const int h  = blockIdx.y;
    const int b  = blockIdx.z;
    const int bh = b * 16 + h;

    const unsigned short* Qhg = wsS + OFF_QH  + (size_t)bh * 2048 * 64;
    const unsigned short* Qlg = wsS + OFF_QL  + (size_t)bh * 2048 * 64;
    const unsigned short* Khg = wsS + OFF_KH  + (size_t)bh * 2048 * 64;
    const unsigned short* Vhg = wsS + OFF_VTH + (size_t)bh * 64 * 2048;
    const float* Mg = mask + (size_t)b * 2048 * 2048;

    // Q frags in registers (this wave's 16 q-rows); scale pre-folded in q
    bf16x8 qfh[2], qfl[2];
    #pragma unroll
    for (int ks = 0; ks < 2; ++ks) {
        const size_t qo = (size_t)(q0 + w * 16 + lm) * 64 + ks * 32 + quad * 8;
        qfh[ks] = *(const bf16x8*)&Qhg[qo];
        qfl[ks] = *(const bf16x8*)&Qlg[qo];
    }

    const int sk8 = tid & 7;
    const int sr0 = tid >> 3;   // 0..31

    // K/V staging registers (hold tile t at loop top)
    bf16x8 rkh[2], rvh[2];
    #pragma unroll
    for (int i = 0; i < 2; ++i) {
        const int r = sr0 + 32 * i;
        rkh[i] = *(const bf16x8*)&Khg[(size_t)r * 64 + sk8 * 8];
        rvh[i] = *(const bf16x8*)&Vhg[(size_t)r * 2048 + sk8 * 8];
    }

    f32x4 o[4] = {};
    float lsum[4] = {0.f, 0.f, 0.f, 0.f};
    const int qwbase = q0 + w * 16 + quad * 4;

    for (int t = 0; t < 32; ++t) {
        const int k0 = t * 64;
        const int p  = t & 1;

        // mask prefetch for THIS tile (used after the barrier)
        float mreg[4][4];
        #pragma unroll
        for (int j = 0; j < 4; ++j)
            #pragma unroll
            for (int ni = 0; ni < 4; ++ni)
                mreg[j][ni] = Mg[(size_t)(qwbase + j) * 2048 + k0 + ni * 16 + lm];

        // write tile t regs into buf p (prev readers ordered by barrier t-1)
        #pragma unroll
        for (int i = 0; i < 2; ++i) {
            const int r = sr0 + 32 * i;
            *(bf16x8*)&Ksh[p][sw8(r, sk8)] = rkh[i];
            *(bf16x8*)&Vth[p][sw8(r, sk8)] = rvh[i];
        }
        // issue NEXT tile's global loads (consumed at t+1 top)
        if (t < 31) {
            #pragma unroll
            for (int i = 0; i < 2; ++i) {
                const int r = sr0 + 32 * i;
                rkh[i] = *(const bf16x8*)&Khg[(size_t)(k0 + 64 + r) * 64 + sk8 * 8];
                rvh[i] = *(const bf16x8*)&Vhg[(size_t)r * 2048 + k0 + 64 + sk8 * 8];
            }
        }
        __syncthreads();   // single barrier per iter

        // S ~= (qh+ql) K_hi^T : 2 MFMA per (ks,ni)
        f32x4 s[4] = {};
        #pragma unroll
        for (int ks = 0; ks < 2; ++ks) {
            #pragma unroll
            for (int ni = 0; ni < 4; ++ni) {
                bf16x8 kh = *(const bf16x8*)&Ksh[p][sw8(ni * 16 + lm, ks * 4 + quad)];
                s[ni] = __builtin_amdgcn_mfma_f32_16x16x32_bf16(qfh[ks], kh, s[ni], 0, 0, 0);
                s[ni] = __builtin_amdgcn_mfma_f32_16x16x32_bf16(qfl[ks], kh, s[ni], 0, 0, 0);
            }
        }

        // p = exp(s * mask); per-lane partial row-sums; P(hi) -> own-wave LDS
        #pragma unroll
        for (int j = 0; j < 4; ++j) {
            #pragma unroll
            for (int ni = 0; ni < 4; ++ni) {
                const float pv = __expf(s[ni][j] * mreg[j][ni]);
                lsum[j] += pv;
                Psh[w][swe(quad * 4 + j, ni * 16 + lm)] = f2b(pv);
            }
        }

        // O += P_hi @ V_hi : 1 MFMA per (ks,ni)
        #pragma unroll
        for (int ks = 0; ks < 2; ++ks) {
            bf16x8 ph = *(const bf16x8*)&Psh[w][sw8(lm, ks * 4 + quad)];
            #pragma unroll
            for (int ni = 0; ni < 4; ++ni) {
                bf16x8 vh = *(const bf16x8*)&Vth[p][sw8(ni * 16 + lm, ks * 4 + quad)];
                o[ni] = __builtin_amdgcn_mfma_f32_16x16x32_bf16(ph, vh, o[ni], 0, 0, 0);
            }
        }
    }

    // epilogue: one cross-lane row-sum reduction, normalize, split-store concat
    #pragma unroll
    for (int j = 0; j < 4; ++j) {
        float ls = lsum[j];
        ls += __shfl_xor(ls, 1);
        ls += __shfl_xor(ls, 2);
        ls += __shfl_xor(ls, 4);
        ls += __shfl_xor(ls, 8);
        const float inv = 1.0f / ls;
        const int q = qwbase + j;
        #pragma unroll
        for (int ni = 0; ni < 4; ++ni) {
            const float val = o[ni][j] * inv;
            const size_t idx = ((size_t)b * 2048 + q) * 1024 + h * 64 + ni * 16 + lm;
            const short hs = f2b(val);
            ch[idx] = hs;
            cl[idx] = f2b(val - b2f(hs));
        }
    }
}

extern "C" void kernel_launch(void* const* d_in, const int* in_sizes, int n_in,
                              void* d_out, int out_size, void* d_ws, size_t ws_size,
                              hipStream_t stream) {
    const float* x    = (const float*)d_in[0];
    const float* mask = (const float*)d_in[1];
    const float* Wq   = (const float*)d_in[2];
    const float* bq   = (const float*)d_in[3];
    const float* Wk   = (const float*)d_in[4];
    const float* bk   = (const float*)d_in[5];
    const float* Wv   = (const float*)d_in[6];
    const float* bv   = (const float*)d_in[7];
    const float* Wo   = (const float*)d_in[8];
    const float* bo   = (const float*)d_in[9];

    unsigned short* wsS = (unsigned short*)d_ws;

    // 1. pre-split: W -> hi (Wq/8); x -> hi+lo
    split_wx<<<8192, 256, 0, stream>>>(Wq, Wk, Wv, Wo, x,
        wsS + OFF_WH, wsS + OFF_XH, wsS + OFF_XL);

    // 2a. Q projection (2-term)
    gemm_2t<<<dim3(8, 32), 256, 0, stream>>>(
        wsS + OFF_XH, wsS + OFF_XL, wsS, bq, nullptr, 0);

    // 2b. K/V projections (1-term)
    gemm_1t<<<dim3(8, 32, 2), 256, 0, stream>>>(
        wsS + OFF_XH, wsS, bk, bv);

    // 3. fused masked-softmax flash attention (dbuf, 1 barrier/iter)
    attn_fast<<<dim3(32, 16, 2), 256, 0, stream>>>(
        wsS, mask, wsS + OFF_CH, wsS + OFF_CL);

    // 4. output projection (2-term)
    gemm_2t<<<dim3(8, 32), 256, 0, stream>>>(
        wsS + OFF_CH, wsS + OFF_CL, wsS, bo, (float*)d_out, 3);
}

// Round 10
// 270.216 us; speedup vs baseline: 1.2027x; 1.1025x over previous
//
#include <hip/hip_runtime.h>
#include <hip/hip_bf16.h>
#include <math.h>

// B=2, N=2048, M=1024, H=16, DK=64. fp32 in/out.
// R10: qkv GEMM re-fused into ONE 768-block launch (3 blocks/CU) with
// block-uniform specialization: z=0 Q (2-term, R7's interleaved loop),
// z=1 K / z=2 V (1-term loop, no Asl anywhere). attn = R9 (dbuf, 1 barrier).
// Precision plan (absmax 9.77e-4 vs 3.96e-3 threshold):
//   Q proj 2t | K,V proj 1t | QK 2t | PV 1t | out proj 2t
// 1/8 attention scale folded into Wq/bq at split time.

typedef __attribute__((ext_vector_type(8))) short bf16x8;
typedef __attribute__((ext_vector_type(4))) float f32x4;

__device__ __forceinline__ short f2b(float f) {
    union { __hip_bfloat16 h; short s; } u;
    u.h = __float2bfloat16(f);   // RNE
    return u.s;
}
__device__ __forceinline__ float b2f(short s) {
    union { short s; __hip_bfloat16 h; } u;
    u.s = s;
    return __bfloat162float(u.h);
}

// XOR-swizzled element offset inside a [rows][64]-bf16 tile (16B blocks).
__device__ __forceinline__ int sw8(int r, int k8) {       // k8 = octet 0..7
    return (r << 6) + ((k8 ^ (r & 7)) << 3);
}
__device__ __forceinline__ int swe(int r, int k) {        // element-level
    return (r << 6) + (((k >> 3) ^ (r & 7)) << 3) + (k & 7);
}

// workspace layout (SHORT offsets). Every plane = 4194304 shorts (8 MB).
#define PLANE   4194304UL
#define OFF_WH  (0UL * PLANE)    // [4][1024][1024] W hi (Wq|Wk|Wv|Wo); Wq pre-scaled 1/8
#define OFF_XH  (1UL * PLANE)    // [4096][1024] x hi
#define OFF_XL  (2UL * PLANE)    // x lo
#define OFF_QH  (3UL * PLANE)    // [B,H,N,DK]
#define OFF_QL  (4UL * PLANE)
#define OFF_KH  (5UL * PLANE)    // hi only
#define OFF_VTH (6UL * PLANE)    // [B,H,DK,N] hi only
#define OFF_CH  (7UL * PLANE)    // [B,N,M] concat hi
#define OFF_CL  (8UL * PLANE)    // concat lo

// ---------------------------------------------------------------------------
// Pre-split: W -> hi only (Wq scaled by 1/8); x -> hi + lo.
// ---------------------------------------------------------------------------
__global__ __launch_bounds__(256) void split_wx(
    const float* __restrict__ Wq, const float* __restrict__ Wk,
    const float* __restrict__ Wv, const float* __restrict__ Wo,
    const float* __restrict__ x,
    unsigned short* __restrict__ wh,
    unsigned short* __restrict__ xh, unsigned short* __restrict__ xl)
{
    const int i = blockIdx.x * 256 + threadIdx.x;   // float4 idx, 2097152 total
    if (i < 1048576) {                               // weights: hi only
        const float* src = (i < 262144) ? Wq : (i < 524288) ? Wk
                         : (i < 786432) ? Wv : Wo;
        const float sc = (i < 262144) ? 0.125f : 1.0f;   // fold attention scale
        const int local = i & 262143;
        float4 v = ((const float4*)src)[local];
        short4 h;
        h.x = f2b(v.x * sc); h.y = f2b(v.y * sc);
        h.z = f2b(v.z * sc); h.w = f2b(v.w * sc);
        ((short4*)(wh + (size_t)(i >> 18) * 1048576))[local] = h;
    } else {                                         // x: hi + lo
        const int local = i - 1048576;
        float4 v = ((const float4*)x)[local];
        short4 h, l;
        h.x = f2b(v.x); l.x = f2b(v.x - b2f(h.x));
        h.y = f2b(v.y); l.y = f2b(v.y - b2f(h.y));
        h.z = f2b(v.z); l.z = f2b(v.z - b2f(h.z));
        h.w = f2b(v.w); l.w = f2b(v.w - b2f(h.w));
        ((short4*)xh)[local] = h;
        ((short4*)xl)[local] = l;
    }
}

// ---------------------------------------------------------------------------
// Fused QKV GEMM, ONE launch (8,32,3) = 768 blocks, 3 blocks/CU.
// z=0: Q = (xh+xl) @ Wq^T (2-term, interleaved R7 loop) -> hi/lo planes.
// z=1: K =  xh     @ Wk^T (1-term)                      -> hi plane.
// z=2: V^T = xh    @ Wv^T (1-term)                      -> hi plane [B,H,DK,N].
// Block-uniform branch; two complete specialized K-loops. LDS 48KB.
// ---------------------------------------------------------------------------
__global__ __launch_bounds__(256, 3) void gemm_qkv(
    unsigned short* __restrict__ wsS,
    const float* __restrict__ bq, const float* __restrict__ bk,
    const float* __restrict__ bv)
{
    __shared__ unsigned short Ash[128 * 64], Asl[128 * 64];
    __shared__ unsigned short Bsh[128 * 64];

    const int mode = blockIdx.z;                     // 0 Q, 1 K, 2 V
    const unsigned short* Ah = wsS + OFF_XH;
    const unsigned short* Al = wsS + OFF_XL;
    const unsigned short* Wh = wsS + OFF_WH + (size_t)mode * 1048576;

    const int tid  = threadIdx.x;
    const int lane = tid & 63;
    const int lm   = lane & 15;
    const int quad = lane >> 4;
    const int w    = tid >> 6;
    const int wr   = w >> 1, wc = w & 1;

    const int row0 = blockIdx.y * 128;
    const int col0 = blockIdx.x * 128;

    const int sk8 = tid & 7;
    const int sr0 = tid >> 3;

    f32x4 acc[4][4] = {};

    if (mode == 0) {
        // ---- 2-term loop (Q) ----
        for (int k0 = 0; k0 < 1024; k0 += 64) {
            if (k0) __syncthreads();
            #pragma unroll
            for (int i = 0; i < 4; ++i) {
                const int r = sr0 + 32 * i;
                *(bf16x8*)&Ash[sw8(r, sk8)] =
                    *(const bf16x8*)&Ah[(size_t)(row0 + r) * 1024 + k0 + sk8 * 8];
                *(bf16x8*)&Asl[sw8(r, sk8)] =
                    *(const bf16x8*)&Al[(size_t)(row0 + r) * 1024 + k0 + sk8 * 8];
                *(bf16x8*)&Bsh[sw8(r, sk8)] =
                    *(const bf16x8*)&Wh[(size_t)(col0 + r) * 1024 + k0 + sk8 * 8];
            }
            __syncthreads();
            #pragma unroll
            for (int ks = 0; ks < 2; ++ks) {
                bf16x8 afh[4], afl[4], bfh[4];
                #pragma unroll
                for (int mi = 0; mi < 4; ++mi) {
                    afh[mi] = *(const bf16x8*)&Ash[sw8(wr * 64 + mi * 16 + lm, ks * 4 + quad)];
                    afl[mi] = *(const bf16x8*)&Asl[sw8(wr * 64 + mi * 16 + lm, ks * 4 + quad)];
                }
                #pragma unroll
                for (int ni = 0; ni < 4; ++ni)
                    bfh[ni] = *(const bf16x8*)&Bsh[sw8(wc * 64 + ni * 16 + lm, ks * 4 + quad)];
                #pragma unroll
                for (int mi = 0; mi < 4; ++mi) {
                    #pragma unroll
                    for (int ni = 0; ni < 4; ++ni) {
                        acc[mi][ni] = __builtin_amdgcn_mfma_f32_16x16x32_bf16(
                            afh[mi], bfh[ni], acc[mi][ni], 0, 0, 0);
                        acc[mi][ni] = __builtin_amdgcn_mfma_f32_16x16x32_bf16(
                            afl[mi], bfh[ni], acc[mi][ni], 0, 0, 0);
                    }
                }
            }
        }
    } else {
        // ---- 1-term loop (K / V) ----
        for (int k0 = 0; k0 < 1024; k0 += 64) {
            if (k0) __syncthreads();
            #pragma unroll
            for (int i = 0; i < 4; ++i) {
                const int r = sr0 + 32 * i;
                *(bf16x8*)&Ash[sw8(r, sk8)] =
                    *(const bf16x8*)&Ah[(size_t)(row0 + r) * 1024 + k0 + sk8 * 8];
                *(bf16x8*)&Bsh[sw8(r, sk8)] =
                    *(const bf16x8*)&Wh[(size_t)(col0 + r) * 1024 + k0 + sk8 * 8];
            }
            __syncthreads();
            #pragma unroll
            for (int ks = 0; ks < 2; ++ks) {
                bf16x8 afh[4], bfh[4];
                #pragma unroll
                for (int mi = 0; mi < 4; ++mi)
                    afh[mi] = *(const bf16x8*)&Ash[sw8(wr * 64 + mi * 16 + lm, ks * 4 + quad)];
                #pragma unroll
                for (int ni = 0; ni < 4; ++ni)
                    bfh[ni] = *(const bf16x8*)&Bsh[sw8(wc * 64 + ni * 16 + lm, ks * 4 + quad)];
                #pragma unroll
                for (int mi = 0; mi < 4; ++mi) {
                    #pragma unroll
                    for (int ni = 0; ni < 4; ++ni)
                        acc[mi][ni] = __builtin_amdgcn_mfma_f32_16x16x32_bf16(
                            afh[mi], bfh[ni], acc[mi][ni], 0, 0, 0);
                }
            }
        }
    }

    unsigned short* qh  = wsS + OFF_QH;
    unsigned short* ql  = wsS + OFF_QL;
    unsigned short* kh  = wsS + OFF_KH;
    unsigned short* vth = wsS + OFF_VTH;
    const float* bias = (mode == 0) ? bq : (mode == 1) ? bk : bv;
    const float bscale = (mode == 0) ? 0.125f : 1.0f;

    // epilogue: C/D layout col=lane&15, row=quad*4+reg
    #pragma unroll
    for (int ni = 0; ni < 4; ++ni) {
        const int f = col0 + wc * 64 + ni * 16 + lm;
        const float bvv = bias[f] * bscale;
        const int h = f >> 6, d = f & 63;
        #pragma unroll
        for (int mi = 0; mi < 4; ++mi) {
            #pragma unroll
            for (int j = 0; j < 4; ++j) {
                const int row = row0 + wr * 64 + mi * 16 + quad * 4 + j;
                const float val = acc[mi][ni][j] + bvv;
                const int bb = row >> 11, n = row & 2047;
                const short hs = f2b(val);
                if (mode == 0) {
                    const size_t idx = ((size_t)(bb * 16 + h) * 2048 + n) * 64 + d;
                    qh[idx] = hs;
                    ql[idx] = f2b(val - b2f(hs));
                } else if (mode == 1) {
                    kh[((size_t)(bb * 16 + h) * 2048 + n) * 64 + d] = hs;
                } else {
                    vth[((size_t)(bb * 16 + h) * 64 + d) * 2048 + n] = hs;
                }
            }
        }
    }
}

// ---------------------------------------------------------------------------
// 2-term GEMM for the output projection: out = (ch+cl) @ Wo^T + bo (fp32).
// ---------------------------------------------------------------------------
__global__ __launch_bounds__(256, 3) void gemm_out(
    const unsigned short* __restrict__ Ah, const unsigned short* __restrict__ Al,
    unsigned short* __restrict__ wsS,
    const float* __restrict__ bias_p, float* __restrict__ oout)
{
    __shared__ unsigned short Ash[128 * 64], Asl[128 * 64];
    __shared__ unsigned short Bsh[128 * 64];

    const unsigned short* Wh = wsS + OFF_WH + 3UL * 1048576;

    const int tid  = threadIdx.x;
    const int lane = tid & 63;
    const int lm   = lane & 15;
    const int quad = lane >> 4;
    const int w    = tid >> 6;
    const int wr   = w >> 1, wc = w & 1;

    const int row0 = blockIdx.y * 128;
    const int col0 = blockIdx.x * 128;

    const int sk8 = tid & 7;
    const int sr0 = tid >> 3;

    f32x4 acc[4][4] = {};

    for (int k0 = 0; k0 < 1024; k0 += 64) {
        if (k0) __syncthreads();
        #pragma unroll
        for (int i = 0; i < 4; ++i) {
            const int r = sr0 + 32 * i;
            *(bf16x8*)&Ash[sw8(r, sk8)] =
                *(const bf16x8*)&Ah[(size_t)(row0 + r) * 1024 + k0 + sk8 * 8];
            *(bf16x8*)&Asl[sw8(r, sk8)] =
                *(const bf16x8*)&Al[(size_t)(row0 + r) * 1024 + k0 + sk8 * 8];
            *(bf16x8*)&Bsh[sw8(r, sk8)] =
                *(const bf16x8*)&Wh[(size_t)(col0 + r) * 1024 + k0 + sk8 * 8];
        }
        __syncthreads();
        #pragma unroll
        for (int ks = 0; ks < 2; ++ks) {
            bf16x8 afh[4], afl[4], bfh[4];
            #pragma unroll
            for (int mi = 0; mi < 4; ++mi) {
                afh[mi] = *(const bf16x8*)&Ash[sw8(wr * 64 + mi * 16 + lm, ks * 4 + quad)];
                afl[mi] = *(const bf16x8*)&Asl[sw8(wr * 64 + mi * 16 + lm, ks * 4 + quad)];
            }
            #pragma unroll
            for (int ni = 0; ni < 4; ++ni)
                bfh[ni] = *(const bf16x8*)&Bsh[sw8(wc * 64 + ni * 16 + lm, ks * 4 + quad)];
            #pragma unroll
            for (int mi = 0; mi < 4; ++mi) {
                #pragma unroll
                for (int ni = 0; ni < 4; ++ni) {
                    acc[mi][ni] = __builtin_amdgcn_mfma_f32_16x16x32_bf16(
                        afh[mi], bfh[ni], acc[mi][ni], 0, 0, 0);
                    acc[mi][ni] = __builtin_amdgcn_mfma_f32_16x16x32_bf16(
                        afl[mi], bfh[ni], acc[mi][ni], 0, 0, 0);
                }
            }
        }
    }

    #pragma unroll
    for (int ni = 0; ni < 4; ++ni) {
        const int f = col0 + wc * 64 + ni * 16 + lm;
        const float bvv = bias_p[f];
        #pragma unroll
        for (int mi = 0; mi < 4; ++mi) {
            #pragma unroll
            for (int j = 0; j < 4; ++j) {
                const int row = row0 + wr * 64 + mi * 16 + quad * 4 + j;
                oout[(size_t)row * 1024 + f] = acc[mi][ni][j] + bvv;
            }
        }
    }
}

// ---------------------------------------------------------------------------
// Flash attention (R9): deferred softmax, K/V LDS double-buffer, one barrier
// per K-tile. QK 2-term, PV 1-term. LDS 40KB -> 4 blocks/CU.
// ---------------------------------------------------------------------------
__global__ __launch_bounds__(256, 4) void attn_fast(
    const unsigned short* __restrict__ wsS, const float* __restrict__ mask,
    unsigned short* __restrict__ ch, unsigned short* __restrict__ cl)
{
    __shared__ unsigned short Ksh[2][64 * 64];   // [buf][kcol][d] hi
    __shared__ unsigned short Vth[2][64 * 64];   // [buf][d][k]    hi
    __shared__ unsigned short Psh[4][16 * 64];   // per-wave [q][k] hi

    const int tid  = threadIdx.x;
    const int lane = tid & 63;
    const int lm   = lane & 15;
    const int quad = lane >> 4;
    const int w    = tid >> 6;

    const int q0 = blockIdx.x * 64;
    const int h  = blockIdx.y;
    const int b  = blockIdx.z;
    const int bh = b * 16 + h;

    const unsigned short* Qhg = wsS + OFF_QH  + (size_t)bh * 2048 * 64;
    const unsigned short* Qlg = wsS + OFF_QL  + (size_t)bh * 2048 * 64;
    const unsigned short* Khg = wsS + OFF_KH  + (size_t)bh * 2048 * 64;
    const unsigned short* Vhg = wsS + OFF_VTH + (size_t)bh * 64 * 2048;
    const float* Mg = mask + (size_t)b * 2048 * 2048;

    // Q frags in registers (this wave's 16 q-rows); scale pre-folded in q
    bf16x8 qfh[2], qfl[2];
    #pragma unroll
    for (int ks = 0; ks < 2; ++ks) {
        const size_t qo = (size_t)(q0 + w * 16 + lm) * 64 + ks * 32 + quad * 8;
        qfh[ks] = *(const bf16x8*)&Qhg[qo];
        qfl[ks] = *(const bf16x8*)&Qlg[qo];
    }

    const int sk8 = tid & 7;
    const int sr0 = tid >> 3;   // 0..31

    bf16x8 rkh[2], rvh[2];
    #pragma unroll
    for (int i = 0; i < 2; ++i) {
        const int r = sr0 + 32 * i;
        rkh[i] = *(const bf16x8*)&Khg[(size_t)r * 64 + sk8 * 8];
        rvh[i] = *(const bf16x8*)&Vhg[(size_t)r * 2048 + sk8 * 8];
    }

    f32x4 o[4] = {};
    float lsum[4] = {0.f, 0.f, 0.f, 0.f};
    const int qwbase = q0 + w * 16 + quad * 4;

    for (int t = 0; t < 32; ++t) {
        const int k0 = t * 64;
        const int p  = t & 1;

        float mreg[4][4];
        #pragma unroll
        for (int j = 0; j < 4; ++j)
            #pragma unroll
            for (int ni = 0; ni < 4; ++ni)
                mreg[j][ni] = Mg[(size_t)(qwbase + j) * 2048 + k0 + ni * 16 + lm];

        #pragma unroll
        for (int i = 0; i < 2; ++i) {
            const int r = sr0 + 32 * i;
            *(bf16x8*)&Ksh[p][sw8(r, sk8)] = rkh[i];
            *(bf16x8*)&Vth[p][sw8(r, sk8)] = rvh[i];
        }
        if (t < 31) {
            #pragma unroll
            for (int i = 0; i < 2; ++i) {
                const int r = sr0 + 32 * i;
                rkh[i] = *(const bf16x8*)&Khg[(size_t)(k0 + 64 + r) * 64 + sk8 * 8];
                rvh[i] = *(const bf16x8*)&Vhg[(size_t)r * 2048 + k0 + 64 + sk8 * 8];
            }
        }
        __syncthreads();   // single barrier per iter

        f32x4 s[4] = {};
        #pragma unroll
        for (int ks = 0; ks < 2; ++ks) {
            #pragma unroll
            for (int ni = 0; ni < 4; ++ni) {
                bf16x8 kh = *(const bf16x8*)&Ksh[p][sw8(ni * 16 + lm, ks * 4 + quad)];
                s[ni] = __builtin_amdgcn_mfma_f32_16x16x32_bf16(qfh[ks], kh, s[ni], 0, 0, 0);
                s[ni] = __builtin_amdgcn_mfma_f32_16x16x32_bf16(qfl[ks], kh, s[ni], 0, 0, 0);
            }
        }

        #pragma unroll
        for (int j = 0; j < 4; ++j) {
            #pragma unroll
            for (int ni = 0; ni < 4; ++ni) {
                const float pv = __expf(s[ni][j] * mreg[j][ni]);
                lsum[j] += pv;
                Psh[w][swe(quad * 4 + j, ni * 16 + lm)] = f2b(pv);
            }
        }

        #pragma unroll
        for (int ks = 0; ks < 2; ++ks) {
            bf16x8 ph = *(const bf16x8*)&Psh[w][sw8(lm, ks * 4 + quad)];
            #pragma unroll
            for (int ni = 0; ni < 4; ++ni) {
                bf16x8 vh = *(const bf16x8*)&Vth[p][sw8(ni * 16 + lm, ks * 4 + quad)];
                o[ni] = __builtin_amdgcn_mfma_f32_16x16x32_bf16(ph, vh, o[ni], 0, 0, 0);
            }
        }
    }

    #pragma unroll
    for (int j = 0; j < 4; ++j) {
        float ls = lsum[j];
        ls += __shfl_xor(ls, 1);
        ls += __shfl_xor(ls, 2);
        ls += __shfl_xor(ls, 4);
        ls += __shfl_xor(ls, 8);
        const float inv = 1.0f / ls;
        const int q = qwbase + j;
        #pragma unroll
        for (int ni = 0; ni < 4; ++ni) {
            const float val = o[ni][j] * inv;
            const size_t idx = ((size_t)b * 2048 + q) * 1024 + h * 64 + ni * 16 + lm;
            const short hs = f2b(val);
            ch[idx] = hs;
            cl[idx] = f2b(val - b2f(hs));
        }
    }
}

extern "C" void kernel_launch(void* const* d_in, const int* in_sizes, int n_in,
                              void* d_out, int out_size, void* d_ws, size_t ws_size,
                              hipStream_t stream) {
    const float* x    = (const float*)d_in[0];
    const float* mask = (const float*)d_in[1];
    const float* Wq   = (const float*)d_in[2];
    const float* bq   = (const float*)d_in[3];
    const float* Wk   = (const float*)d_in[4];
    const float* bk   = (const float*)d_in[5];
    const float* Wv   = (const float*)d_in[6];
    const float* bv   = (const float*)d_in[7];
    const float* Wo   = (const float*)d_in[8];
    const float* bo   = (const float*)d_in[9];

    unsigned short* wsS = (unsigned short*)d_ws;

    // 1. pre-split: W -> hi (Wq/8); x -> hi+lo
    split_wx<<<8192, 256, 0, stream>>>(Wq, Wk, Wv, Wo, x,
        wsS + OFF_WH, wsS + OFF_XH, wsS + OFF_XL);

    // 2. Q/K/V projections, ONE 768-block launch (Q 2t; K,V 1t)
    gemm_qkv<<<dim3(8, 32, 3), 256, 0, stream>>>(wsS, bq, bk, bv);

    // 3. fused masked-softmax flash attention (dbuf, 1 barrier/iter)
    attn_fast<<<dim3(32, 16, 2), 256, 0, stream>>>(
        wsS, mask, wsS + OFF_CH, wsS + OFF_CL);

    // 4. output projection (2-term)
    gemm_out<<<dim3(8, 32), 256, 0, stream>>>(
        wsS + OFF_CH, wsS + OFF_CL, wsS, bo, (float*)d_out);
}

// Round 11
// 269.164 us; speedup vs baseline: 1.2074x; 1.0039x over previous
//
#include <hip/hip_runtime.h>
#include <hip/hip_bf16.h>
#include <math.h>

// B=2, N=2048, M=1024, H=16, DK=64. fp32 in/out.
// R11 = R10 + async global->LDS staging (__builtin_amdgcn_global_load_lds,
// width=16) for all GEMM planes and attn K/V tiles. The XOR bank swizzle is
// realized on the GLOBAL address side (lane l loads octet (l&7)^((l>>3)&7)),
// so LDS slot (r,s) holds octet s^(r&7) — identical to sw8 reads. Bit-exact
// vs R10. Precision plan: Q proj 2t | K,V 1t | QK 2t | PV 1t | out 2t.
// 1/8 attention scale folded into Wq/bq.

typedef __attribute__((ext_vector_type(8))) short bf16x8;
typedef __attribute__((ext_vector_type(4))) float f32x4;

typedef __attribute__((address_space(1))) void gvoid;   // global
typedef __attribute__((address_space(3))) void lvoid;   // LDS

// async 16B/lane global->LDS copy: 64 lanes -> 1KB at wave-uniform lds base
__device__ __forceinline__ void gll16(const void* g, void* l) {
    __builtin_amdgcn_global_load_lds(
        (gvoid*)(unsigned long long)g,
        (lvoid*)(unsigned int)(unsigned long long)l,   // low 32b = LDS offset
        16, 0, 0);
}

__device__ __forceinline__ short f2b(float f) {
    union { __hip_bfloat16 h; short s; } u;
    u.h = __float2bfloat16(f);   // RNE
    return u.s;
}
__device__ __forceinline__ float b2f(short s) {
    union { short s; __hip_bfloat16 h; } u;
    u.s = s;
    return __bfloat162float(u.h);
}

// XOR-swizzled element offset inside a [rows][64]-bf16 tile (16B blocks).
__device__ __forceinline__ int sw8(int r, int k8) {       // k8 = octet 0..7
    return (r << 6) + ((k8 ^ (r & 7)) << 3);
}
__device__ __forceinline__ int swe(int r, int k) {        // element-level
    return (r << 6) + (((k >> 3) ^ (r & 7)) << 3) + (k & 7);
}

// workspace layout (SHORT offsets). Every plane = 4194304 shorts (8 MB).
#define PLANE   4194304UL
#define OFF_WH  (0UL * PLANE)    // [4][1024][1024] W hi; Wq pre-scaled 1/8
#define OFF_XH  (1UL * PLANE)    // [4096][1024] x hi
#define OFF_XL  (2UL * PLANE)    // x lo
#define OFF_QH  (3UL * PLANE)    // [B,H,N,DK]
#define OFF_QL  (4UL * PLANE)
#define OFF_KH  (5UL * PLANE)    // hi only
#define OFF_VTH (6UL * PLANE)    // [B,H,DK,N] hi only
#define OFF_CH  (7UL * PLANE)    // [B,N,M] concat hi
#define OFF_CL  (8UL * PLANE)    // concat lo

// ---------------------------------------------------------------------------
// Pre-split: W -> hi only (Wq scaled by 1/8); x -> hi + lo.
// ---------------------------------------------------------------------------
__global__ __launch_bounds__(256) void split_wx(
    const float* __restrict__ Wq, const float* __restrict__ Wk,
    const float* __restrict__ Wv, const float* __restrict__ Wo,
    const float* __restrict__ x,
    unsigned short* __restrict__ wh,
    unsigned short* __restrict__ xh, unsigned short* __restrict__ xl)
{
    const int i = blockIdx.x * 256 + threadIdx.x;   // float4 idx, 2097152 total
    if (i < 1048576) {                               // weights: hi only
        const float* src = (i < 262144) ? Wq : (i < 524288) ? Wk
                         : (i < 786432) ? Wv : Wo;
        const float sc = (i < 262144) ? 0.125f : 1.0f;   // fold attention scale
        const int local = i & 262143;
        float4 v = ((const float4*)src)[local];
        short4 h;
        h.x = f2b(v.x * sc); h.y = f2b(v.y * sc);
        h.z = f2b(v.z * sc); h.w = f2b(v.w * sc);
        ((short4*)(wh + (size_t)(i >> 18) * 1048576))[local] = h;
    } else {                                         // x: hi + lo
        const int local = i - 1048576;
        float4 v = ((const float4*)x)[local];
        short4 h, l;
        h.x = f2b(v.x); l.x = f2b(v.x - b2f(h.x));
        h.y = f2b(v.y); l.y = f2b(v.y - b2f(h.y));
        h.z = f2b(v.z); l.z = f2b(v.z - b2f(h.z));
        h.w = f2b(v.w); l.w = f2b(v.w - b2f(h.w));
        ((short4*)xh)[local] = h;
        ((short4*)xl)[local] = l;
    }
}

// ---------------------------------------------------------------------------
// Fused QKV GEMM, ONE launch (8,32,3) = 768 blocks, 3 blocks/CU, LDS 48KB.
// z=0: Q 2-term -> hi/lo planes; z=1: K 1-term; z=2: V^T 1-term.
// Staging via global_load_lds (async, swizzle folded into global address).
// ---------------------------------------------------------------------------
__global__ __launch_bounds__(256, 3) void gemm_qkv(
    unsigned short* __restrict__ wsS,
    const float* __restrict__ bq, const float* __restrict__ bk,
    const float* __restrict__ bv)
{
    __shared__ unsigned short Ash[128 * 64], Asl[128 * 64];
    __shared__ unsigned short Bsh[128 * 64];

    const int mode = blockIdx.z;                     // 0 Q, 1 K, 2 V
    const unsigned short* Ah = wsS + OFF_XH;
    const unsigned short* Al = wsS + OFF_XL;
    const unsigned short* Wh = wsS + OFF_WH + (size_t)mode * 1048576;

    const int tid  = threadIdx.x;
    const int lane = tid & 63;
    const int lm   = lane & 15;
    const int quad = lane >> 4;
    const int w    = tid >> 6;
    const int wr   = w >> 1, wc = w & 1;

    const int row0 = blockIdx.y * 128;
    const int col0 = blockIdx.x * 128;

    // staging source pattern: lane l -> row +(l>>3), octet (l&7)^((l>>3)&7)
    const int srow = lane >> 3;
    const int soct = (lane & 7) ^ (srow & 7);

    f32x4 acc[4][4] = {};

    if (mode == 0) {
        // ---- 2-term loop (Q) ----
        for (int k0 = 0; k0 < 1024; k0 += 64) {
            if (k0) __syncthreads();
            #pragma unroll
            for (int i = 0; i < 4; ++i) {
                const int rb = w * 32 + i * 8;       // wave-uniform row base
                gll16(&Ah[(size_t)(row0 + rb + srow) * 1024 + k0 + soct * 8],
                      &Ash[rb * 64]);
                gll16(&Al[(size_t)(row0 + rb + srow) * 1024 + k0 + soct * 8],
                      &Asl[rb * 64]);
                gll16(&Wh[(size_t)(col0 + rb + srow) * 1024 + k0 + soct * 8],
                      &Bsh[rb * 64]);
            }
            __syncthreads();
            #pragma unroll
            for (int ks = 0; ks < 2; ++ks) {
                bf16x8 afh[4], afl[4], bfh[4];
                #pragma unroll
                for (int mi = 0; mi < 4; ++mi) {
                    afh[mi] = *(const bf16x8*)&Ash[sw8(wr * 64 + mi * 16 + lm, ks * 4 + quad)];
                    afl[mi] = *(const bf16x8*)&Asl[sw8(wr * 64 + mi * 16 + lm, ks * 4 + quad)];
                }
                #pragma unroll
                for (int ni = 0; ni < 4; ++ni)
                    bfh[ni] = *(const bf16x8*)&Bsh[sw8(wc * 64 + ni * 16 + lm, ks * 4 + quad)];
                #pragma unroll
                for (int mi = 0; mi < 4; ++mi) {
                    #pragma unroll
                    for (int ni = 0; ni < 4; ++ni) {
                        acc[mi][ni] = __builtin_amdgcn_mfma_f32_16x16x32_bf16(
                            afh[mi], bfh[ni], acc[mi][ni], 0, 0, 0);
                        acc[mi][ni] = __builtin_amdgcn_mfma_f32_16x16x32_bf16(
                            afl[mi], bfh[ni], acc[mi][ni], 0, 0, 0);
                    }
                }
            }
        }
    } else {
        // ---- 1-term loop (K / V) ----
        for (int k0 = 0; k0 < 1024; k0 += 64) {
            if (k0) __syncthreads();
            #pragma unroll
            for (int i = 0; i < 4; ++i) {
                const int rb = w * 32 + i * 8;
                gll16(&Ah[(size_t)(row0 + rb + srow) * 1024 + k0 + soct * 8],
                      &Ash[rb * 64]);
                gll16(&Wh[(size_t)(col0 + rb + srow) * 1024 + k0 + soct * 8],
                      &Bsh[rb * 64]);
            }
            __syncthreads();
            #pragma unroll
            for (int ks = 0; ks < 2; ++ks) {
                bf16x8 afh[4], bfh[4];
                #pragma unroll
                for (int mi = 0; mi < 4; ++mi)
                    afh[mi] = *(const bf16x8*)&Ash[sw8(wr * 64 + mi * 16 + lm, ks * 4 + quad)];
                #pragma unroll
                for (int ni = 0; ni < 4; ++ni)
                    bfh[ni] = *(const bf16x8*)&Bsh[sw8(wc * 64 + ni * 16 + lm, ks * 4 + quad)];
                #pragma unroll
                for (int mi = 0; mi < 4; ++mi) {
                    #pragma unroll
                    for (int ni = 0; ni < 4; ++ni)
                        acc[mi][ni] = __builtin_amdgcn_mfma_f32_16x16x32_bf16(
                            afh[mi], bfh[ni], acc[mi][ni], 0, 0, 0);
                }
            }
        }
    }

    unsigned short* qh  = wsS + OFF_QH;
    unsigned short* ql  = wsS + OFF_QL;
    unsigned short* kh  = wsS + OFF_KH;
    unsigned short* vth = wsS + OFF_VTH;
    const float* bias = (mode == 0) ? bq : (mode == 1) ? bk : bv;
    const float bscale = (mode == 0) ? 0.125f : 1.0f;

    // epilogue: C/D layout col=lane&15, row=quad*4+reg
    #pragma unroll
    for (int ni = 0; ni < 4; ++ni) {
        const int f = col0 + wc * 64 + ni * 16 + lm;
        const float bvv = bias[f] * bscale;
        const int h = f >> 6, d = f & 63;
        #pragma unroll
        for (int mi = 0; mi < 4; ++mi) {
            #pragma unroll
            for (int j = 0; j < 4; ++j) {
                const int row = row0 + wr * 64 + mi * 16 + quad * 4 + j;
                const float val = acc[mi][ni][j] + bvv;
                const int bb = row >> 11, n = row & 2047;
                const short hs = f2b(val);
                if (mode == 0) {
                    const size_t idx = ((size_t)(bb * 16 + h) * 2048 + n) * 64 + d;
                    qh[idx] = hs;
                    ql[idx] = f2b(val - b2f(hs));
                } else if (mode == 1) {
                    kh[((size_t)(bb * 16 + h) * 2048 + n) * 64 + d] = hs;
                } else {
                    vth[((size_t)(bb * 16 + h) * 64 + d) * 2048 + n] = hs;
                }
            }
        }
    }
}

// ---------------------------------------------------------------------------
// 2-term GEMM, output projection: out = (ch+cl) @ Wo^T + bo (fp32).
// Staging via global_load_lds.
// ---------------------------------------------------------------------------
__global__ __launch_bounds__(256, 3) void gemm_out(
    const unsigned short* __restrict__ Ah, const unsigned short* __restrict__ Al,
    unsigned short* __restrict__ wsS,
    const float* __restrict__ bias_p, float* __restrict__ oout)
{
    __shared__ unsigned short Ash[128 * 64], Asl[128 * 64];
    __shared__ unsigned short Bsh[128 * 64];

    const unsigned short* Wh = wsS + OFF_WH + 3UL * 1048576;

    const int tid  = threadIdx.x;
    const int lane = tid & 63;
    const int lm   = lane & 15;
    const int quad = lane >> 4;
    const int w    = tid >> 6;
    const int wr   = w >> 1, wc = w & 1;

    const int row0 = blockIdx.y * 128;
    const int col0 = blockIdx.x * 128;

    const int srow = lane >> 3;
    const int soct = (lane & 7) ^ (srow & 7);

    f32x4 acc[4][4] = {};

    for (int k0 = 0; k0 < 1024; k0 += 64) {
        if (k0) __syncthreads();
        #pragma unroll
        for (int i = 0; i < 4; ++i) {
            const int rb = w * 32 + i * 8;
            gll16(&Ah[(size_t)(row0 + rb + srow) * 1024 + k0 + soct * 8],
                  &Ash[rb * 64]);
            gll16(&Al[(size_t)(row0 + rb + srow) * 1024 + k0 + soct * 8],
                  &Asl[rb * 64]);
            gll16(&Wh[(size_t)(col0 + rb + srow) * 1024 + k0 + soct * 8],
                  &Bsh[rb * 64]);
        }
        __syncthreads();
        #pragma unroll
        for (int ks = 0; ks < 2; ++ks) {
            bf16x8 afh[4], afl[4], bfh[4];
            #pragma unroll
            for (int mi = 0; mi < 4; ++mi) {
                afh[mi] = *(const bf16x8*)&Ash[sw8(wr * 64 + mi * 16 + lm, ks * 4 + quad)];
                afl[mi] = *(const bf16x8*)&Asl[sw8(wr * 64 + mi * 16 + lm, ks * 4 + quad)];
            }
            #pragma unroll
            for (int ni = 0; ni < 4; ++ni)
                bfh[ni] = *(const bf16x8*)&Bsh[sw8(wc * 64 + ni * 16 + lm, ks * 4 + quad)];
            #pragma unroll
            for (int mi = 0; mi < 4; ++mi) {
                #pragma unroll
                for (int ni = 0; ni < 4; ++ni) {
                    acc[mi][ni] = __builtin_amdgcn_mfma_f32_16x16x32_bf16(
                        afh[mi], bfh[ni], acc[mi][ni], 0, 0, 0);
                    acc[mi][ni] = __builtin_amdgcn_mfma_f32_16x16x32_bf16(
                        afl[mi], bfh[ni], acc[mi][ni], 0, 0, 0);
                }
            }
        }
    }

    #pragma unroll
    for (int ni = 0; ni < 4; ++ni) {
        const int f = col0 + wc * 64 + ni * 16 + lm;
        const float bvv = bias_p[f];
        #pragma unroll
        for (int mi = 0; mi < 4; ++mi) {
            #pragma unroll
            for (int j = 0; j < 4; ++j) {
                const int row = row0 + wr * 64 + mi * 16 + quad * 4 + j;
                oout[(size_t)row * 1024 + f] = acc[mi][ni][j] + bvv;
            }
        }
    }
}

// ---------------------------------------------------------------------------
// Flash attention: deferred softmax, K/V LDS double-buffer via
// global_load_lds (async), ONE barrier per K-tile drains vmcnt exactly once.
// QK 2-term, PV 1-term. LDS 40KB -> 4 blocks/CU.
// ---------------------------------------------------------------------------
__global__ __launch_bounds__(256, 4) void attn_fast(
    const unsigned short* __restrict__ wsS, const float* __restrict__ mask,
    unsigned short* __restrict__ ch, unsigned short* __restrict__ cl)
{
    __shared__ unsigned short Ksh[2][64 * 64];   // [buf][kcol][d] hi
    __shared__ unsigned short Vth[2][64 * 64];   // [buf][d][k]    hi
    __shared__ unsigned short Psh[4][16 * 64];   // per-wave [q][k] hi

    const int tid  = threadIdx.x;
    const int lane = tid & 63;
    const int lm   = lane & 15;
    const int quad = lane >> 4;
    const int w    = tid >> 6;

    const int q0 = blockIdx.x * 64;
    const int h  = blockIdx.y;
    const int b  = blockIdx.z;
    const int bh = b * 16 + h;

    const unsigned short* Qhg = wsS + OFF_QH  + (size_t)bh * 2048 * 64;
    const unsigned short* Qlg = wsS + OFF_QL  + (size_t)bh * 2048 * 64;
    const unsigned short* Khg = wsS + OFF_KH  + (size_t)bh * 2048 * 64;
    const unsigned short* Vhg = wsS + OFF_VTH + (size_t)bh * 64 * 2048;
    const float* Mg = mask + (size_t)b * 2048 * 2048;

    // Q frags in registers (this wave's 16 q-rows); scale pre-folded in q
    bf16x8 qfh[2], qfl[2];
    #pragma unroll
    for (int ks = 0; ks < 2; ++ks) {
        const size_t qo = (size_t)(q0 + w * 16 + lm) * 64 + ks * 32 + quad * 8;
        qfh[ks] = *(const bf16x8*)&Qhg[qo];
        qfl[ks] = *(const bf16x8*)&Qlg[qo];
    }

    const int srow = lane >> 3;
    const int soct = (lane & 7) ^ (srow & 7);

    // prologue: async-load tile 0 into buf 0 (2 calls/wave per matrix)
    #pragma unroll
    for (int i = 0; i < 2; ++i) {
        const int rb = w * 16 + i * 8;               // wave-uniform row base
        gll16(&Khg[(size_t)(rb + srow) * 64 + soct * 8],       &Ksh[0][rb * 64]);
        gll16(&Vhg[(size_t)(rb + srow) * 2048 + soct * 8],     &Vth[0][rb * 64]);
    }

    f32x4 o[4] = {};
    float lsum[4] = {0.f, 0.f, 0.f, 0.f};
    const int qwbase = q0 + w * 16 + quad * 4;

    for (int t = 0; t < 32; ++t) {
        const int k0 = t * 64;
        const int p  = t & 1;

        __syncthreads();   // drains vmcnt -> tile t resident in buf p

        // async-issue tile t+1 into buf 1-p (lands before next barrier)
        if (t < 31) {
            #pragma unroll
            for (int i = 0; i < 2; ++i) {
                const int rb = w * 16 + i * 8;
                gll16(&Khg[(size_t)(k0 + 64 + rb + srow) * 64 + soct * 8],
                      &Ksh[1 - p][rb * 64]);
                gll16(&Vhg[(size_t)(rb + srow) * 2048 + k0 + 64 + soct * 8],
                      &Vth[1 - p][rb * 64]);
            }
        }

        float mreg[4][4];
        #pragma unroll
        for (int j = 0; j < 4; ++j)
            #pragma unroll
            for (int ni = 0; ni < 4; ++ni)
                mreg[j][ni] = Mg[(size_t)(qwbase + j) * 2048 + k0 + ni * 16 + lm];

        // S ~= (qh+ql) K_hi^T : 2 MFMA per (ks,ni)
        f32x4 s[4] = {};
        #pragma unroll
        for (int ks = 0; ks < 2; ++ks) {
            #pragma unroll
            for (int ni = 0; ni < 4; ++ni) {
                bf16x8 kh = *(const bf16x8*)&Ksh[p][sw8(ni * 16 + lm, ks * 4 + quad)];
                s[ni] = __builtin_amdgcn_mfma_f32_16x16x32_bf16(qfh[ks], kh, s[ni], 0, 0, 0);
                s[ni] = __builtin_amdgcn_mfma_f32_16x16x32_bf16(qfl[ks], kh, s[ni], 0, 0, 0);
            }
        }

        // p = exp(s * mask); per-lane partial row-sums; P(hi) -> own-wave LDS
        #pragma unroll
        for (int j = 0; j < 4; ++j) {
            #pragma unroll
            for (int ni = 0; ni < 4; ++ni) {
                const float pv = __expf(s[ni][j] * mreg[j][ni]);
                lsum[j] += pv;
                Psh[w][swe(quad * 4 + j, ni * 16 + lm)] = f2b(pv);
            }
        }

        // O += P_hi @ V_hi : 1 MFMA per (ks,ni)
        #pragma unroll
        for (int ks = 0; ks < 2; ++ks) {
            bf16x8 ph = *(const bf16x8*)&Psh[w][sw8(lm, ks * 4 + quad)];
            #pragma unroll
            for (int ni = 0; ni < 4; ++ni) {
                bf16x8 vh = *(const bf16x8*)&Vth[p][sw8(ni * 16 + lm, ks * 4 + quad)];
                o[ni] = __builtin_amdgcn_mfma_f32_16x16x32_bf16(ph, vh, o[ni], 0, 0, 0);
            }
        }
    }

    // epilogue: one cross-lane row-sum reduction, normalize, split-store concat
    #pragma unroll
    for (int j = 0; j < 4; ++j) {
        float ls = lsum[j];
        ls += __shfl_xor(ls, 1);
        ls += __shfl_xor(ls, 2);
        ls += __shfl_xor(ls, 4);
        ls += __shfl_xor(ls, 8);
        const float inv = 1.0f / ls;
        const int q = qwbase + j;
        #pragma unroll
        for (int ni = 0; ni < 4; ++ni) {
            const float val = o[ni][j] * inv;
            const size_t idx = ((size_t)b * 2048 + q) * 1024 + h * 64 + ni * 16 + lm;
            const short hs = f2b(val);
            ch[idx] = hs;
            cl[idx] = f2b(val - b2f(hs));
        }
    }
}

extern "C" void kernel_launch(void* const* d_in, const int* in_sizes, int n_in,
                              void* d_out, int out_size, void* d_ws, size_t ws_size,
                              hipStream_t stream) {
    const float* x    = (const float*)d_in[0];
    const float* mask = (const float*)d_in[1];
    const float* Wq   = (const float*)d_in[2];
    const float* bq   = (const float*)d_in[3];
    const float* Wk   = (const float*)d_in[4];
    const float* bk   = (const float*)d_in[5];
    const float* Wv   = (const float*)d_in[6];
    const float* bv   = (const float*)d_in[7];
    const float* Wo   = (const float*)d_in[8];
    const float* bo   = (const float*)d_in[9];

    unsigned short* wsS = (unsigned short*)d_ws;

    // 1. pre-split: W -> hi (Wq/8); x -> hi+lo
    split_wx<<<8192, 256, 0, stream>>>(Wq, Wk, Wv, Wo, x,
        wsS + OFF_WH, wsS + OFF_XH, wsS + OFF_XL);

    // 2. Q/K/V projections, ONE 768-block launch (Q 2t; K,V 1t)
    gemm_qkv<<<dim3(8, 32, 3), 256, 0, stream>>>(wsS, bq, bk, bv);

    // 3. fused masked-softmax flash attention (async dbuf, 1 barrier/iter)
    attn_fast<<<dim3(32, 16, 2), 256, 0, stream>>>(
        wsS, mask, wsS + OFF_CH, wsS + OFF_CL);

    // 4. output projection (2-term)
    gemm_out<<<dim3(8, 32), 256, 0, stream>>>(
        wsS + OFF_CH, wsS + OFF_CL, wsS, bo, (float*)d_out);
}

// Round 12
// 267.214 us; speedup vs baseline: 1.2162x; 1.0073x over previous
//
#include <hip/hip_runtime.h>
#include <hip/hip_bf16.h>
#include <math.h>

// B=2, N=2048, M=1024, H=16, DK=64. fp32 in/out.
// R12 = R11 GEMMs (unchanged, async-staged) + attn with 128-row blocks:
// each wave owns 32 q-rows (2 strips) so K/V b128 frag reads are reused 2x
// -> LDS-pipe cycles per unit work drop ~31% (attn shown LDS-bound in R11:
// ~73% LDS pipe busy from 16 ds_write_b16 + 18 ds_read_b128 per wave-iter).
// launch_bounds(256,2): 256-VGPR cap (R6's 128-cap remat failure avoided).
// Precision plan: Q proj 2t | K,V 1t | QK 2t | PV 1t | out 2t. Bit-exact R11.

typedef __attribute__((ext_vector_type(8))) short bf16x8;
typedef __attribute__((ext_vector_type(4))) float f32x4;

typedef __attribute__((address_space(1))) void gvoid;   // global
typedef __attribute__((address_space(3))) void lvoid;   // LDS

// async 16B/lane global->LDS copy: 64 lanes -> 1KB at wave-uniform lds base
__device__ __forceinline__ void gll16(const void* g, void* l) {
    __builtin_amdgcn_global_load_lds(
        (gvoid*)(unsigned long long)g,
        (lvoid*)(unsigned int)(unsigned long long)l,   // low 32b = LDS offset
        16, 0, 0);
}

__device__ __forceinline__ short f2b(float f) {
    union { __hip_bfloat16 h; short s; } u;
    u.h = __float2bfloat16(f);   // RNE
    return u.s;
}
__device__ __forceinline__ float b2f(short s) {
    union { short s; __hip_bfloat16 h; } u;
    u.s = s;
    return __bfloat162float(u.h);
}

// XOR-swizzled element offset inside a [rows][64]-bf16 tile (16B blocks).
__device__ __forceinline__ int sw8(int r, int k8) {       // k8 = octet 0..7
    return (r << 6) + ((k8 ^ (r & 7)) << 3);
}
__device__ __forceinline__ int swe(int r, int k) {        // element-level
    return (r << 6) + (((k >> 3) ^ (r & 7)) << 3) + (k & 7);
}

// workspace layout (SHORT offsets). Every plane = 4194304 shorts (8 MB).
#define PLANE   4194304UL
#define OFF_WH  (0UL * PLANE)    // [4][1024][1024] W hi; Wq pre-scaled 1/8
#define OFF_XH  (1UL * PLANE)    // [4096][1024] x hi
#define OFF_XL  (2UL * PLANE)    // x lo
#define OFF_QH  (3UL * PLANE)    // [B,H,N,DK]
#define OFF_QL  (4UL * PLANE)
#define OFF_KH  (5UL * PLANE)    // hi only
#define OFF_VTH (6UL * PLANE)    // [B,H,DK,N] hi only
#define OFF_CH  (7UL * PLANE)    // [B,N,M] concat hi
#define OFF_CL  (8UL * PLANE)    // concat lo

// ---------------------------------------------------------------------------
// Pre-split: W -> hi only (Wq scaled by 1/8); x -> hi + lo.
// ---------------------------------------------------------------------------
__global__ __launch_bounds__(256) void split_wx(
    const float* __restrict__ Wq, const float* __restrict__ Wk,
    const float* __restrict__ Wv, const float* __restrict__ Wo,
    const float* __restrict__ x,
    unsigned short* __restrict__ wh,
    unsigned short* __restrict__ xh, unsigned short* __restrict__ xl)
{
    const int i = blockIdx.x * 256 + threadIdx.x;   // float4 idx, 2097152 total
    if (i < 1048576) {                               // weights: hi only
        const float* src = (i < 262144) ? Wq : (i < 524288) ? Wk
                         : (i < 786432) ? Wv : Wo;
        const float sc = (i < 262144) ? 0.125f : 1.0f;   // fold attention scale
        const int local = i & 262143;
        float4 v = ((const float4*)src)[local];
        short4 h;
        h.x = f2b(v.x * sc); h.y = f2b(v.y * sc);
        h.z = f2b(v.z * sc); h.w = f2b(v.w * sc);
        ((short4*)(wh + (size_t)(i >> 18) * 1048576))[local] = h;
    } else {                                         // x: hi + lo
        const int local = i - 1048576;
        float4 v = ((const float4*)x)[local];
        short4 h, l;
        h.x = f2b(v.x); l.x = f2b(v.x - b2f(h.x));
        h.y = f2b(v.y); l.y = f2b(v.y - b2f(h.y));
        h.z = f2b(v.z); l.z = f2b(v.z - b2f(h.z));
        h.w = f2b(v.w); l.w = f2b(v.w - b2f(h.w));
        ((short4*)xh)[local] = h;
        ((short4*)xl)[local] = l;
    }
}

// ---------------------------------------------------------------------------
// Fused QKV GEMM (unchanged R11): ONE launch (8,32,3), async staging.
// z=0: Q 2-term -> hi/lo planes; z=1: K 1-term; z=2: V^T 1-term.
// ---------------------------------------------------------------------------
__global__ __launch_bounds__(256, 3) void gemm_qkv(
    unsigned short* __restrict__ wsS,
    const float* __restrict__ bq, const float* __restrict__ bk,
    const float* __restrict__ bv)
{
    __shared__ unsigned short Ash[128 * 64], Asl[128 * 64];
    __shared__ unsigned short Bsh[128 * 64];

    const int mode = blockIdx.z;                     // 0 Q, 1 K, 2 V
    const unsigned short* Ah = wsS + OFF_XH;
    const unsigned short* Al = wsS + OFF_XL;
    const unsigned short* Wh = wsS + OFF_WH + (size_t)mode * 1048576;

    const int tid  = threadIdx.x;
    const int lane = tid & 63;
    const int lm   = lane & 15;
    const int quad = lane >> 4;
    const int w    = tid >> 6;
    const int wr   = w >> 1, wc = w & 1;

    const int row0 = blockIdx.y * 128;
    const int col0 = blockIdx.x * 128;

    const int srow = lane >> 3;
    const int soct = (lane & 7) ^ (srow & 7);

    f32x4 acc[4][4] = {};

    if (mode == 0) {
        for (int k0 = 0; k0 < 1024; k0 += 64) {
            if (k0) __syncthreads();
            #pragma unroll
            for (int i = 0; i < 4; ++i) {
                const int rb = w * 32 + i * 8;
                gll16(&Ah[(size_t)(row0 + rb + srow) * 1024 + k0 + soct * 8],
                      &Ash[rb * 64]);
                gll16(&Al[(size_t)(row0 + rb + srow) * 1024 + k0 + soct * 8],
                      &Asl[rb * 64]);
                gll16(&Wh[(size_t)(col0 + rb + srow) * 1024 + k0 + soct * 8],
                      &Bsh[rb * 64]);
            }
            __syncthreads();
            #pragma unroll
            for (int ks = 0; ks < 2; ++ks) {
                bf16x8 afh[4], afl[4], bfh[4];
                #pragma unroll
                for (int mi = 0; mi < 4; ++mi) {
                    afh[mi] = *(const bf16x8*)&Ash[sw8(wr * 64 + mi * 16 + lm, ks * 4 + quad)];
                    afl[mi] = *(const bf16x8*)&Asl[sw8(wr * 64 + mi * 16 + lm, ks * 4 + quad)];
                }
                #pragma unroll
                for (int ni = 0; ni < 4; ++ni)
                    bfh[ni] = *(const bf16x8*)&Bsh[sw8(wc * 64 + ni * 16 + lm, ks * 4 + quad)];
                #pragma unroll
                for (int mi = 0; mi < 4; ++mi) {
                    #pragma unroll
                    for (int ni = 0; ni < 4; ++ni) {
                        acc[mi][ni] = __builtin_amdgcn_mfma_f32_16x16x32_bf16(
                            afh[mi], bfh[ni], acc[mi][ni], 0, 0, 0);
                        acc[mi][ni] = __builtin_amdgcn_mfma_f32_16x16x32_bf16(
                            afl[mi], bfh[ni], acc[mi][ni], 0, 0, 0);
                    }
                }
            }
        }
    } else {
        for (int k0 = 0; k0 < 1024; k0 += 64) {
            if (k0) __syncthreads();
            #pragma unroll
            for (int i = 0; i < 4; ++i) {
                const int rb = w * 32 + i * 8;
                gll16(&Ah[(size_t)(row0 + rb + srow) * 1024 + k0 + soct * 8],
                      &Ash[rb * 64]);
                gll16(&Wh[(size_t)(col0 + rb + srow) * 1024 + k0 + soct * 8],
                      &Bsh[rb * 64]);
            }
            __syncthreads();
            #pragma unroll
            for (int ks = 0; ks < 2; ++ks) {
                bf16x8 afh[4], bfh[4];
                #pragma unroll
                for (int mi = 0; mi < 4; ++mi)
                    afh[mi] = *(const bf16x8*)&Ash[sw8(wr * 64 + mi * 16 + lm, ks * 4 + quad)];
                #pragma unroll
                for (int ni = 0; ni < 4; ++ni)
                    bfh[ni] = *(const bf16x8*)&Bsh[sw8(wc * 64 + ni * 16 + lm, ks * 4 + quad)];
                #pragma unroll
                for (int mi = 0; mi < 4; ++mi) {
                    #pragma unroll
                    for (int ni = 0; ni < 4; ++ni)
                        acc[mi][ni] = __builtin_amdgcn_mfma_f32_16x16x32_bf16(
                            afh[mi], bfh[ni], acc[mi][ni], 0, 0, 0);
                }
            }
        }
    }

    unsigned short* qh  = wsS + OFF_QH;
    unsigned short* ql  = wsS + OFF_QL;
    unsigned short* kh  = wsS + OFF_KH;
    unsigned short* vth = wsS + OFF_VTH;
    const float* bias = (mode == 0) ? bq : (mode == 1) ? bk : bv;
    const float bscale = (mode == 0) ? 0.125f : 1.0f;

    #pragma unroll
    for (int ni = 0; ni < 4; ++ni) {
        const int f = col0 + wc * 64 + ni * 16 + lm;
        const float bvv = bias[f] * bscale;
        const int h = f >> 6, d = f & 63;
        #pragma unroll
        for (int mi = 0; mi < 4; ++mi) {
            #pragma unroll
            for (int j = 0; j < 4; ++j) {
                const int row = row0 + wr * 64 + mi * 16 + quad * 4 + j;
                const float val = acc[mi][ni][j] + bvv;
                const int bb = row >> 11, n = row & 2047;
                const short hs = f2b(val);
                if (mode == 0) {
                    const size_t idx = ((size_t)(bb * 16 + h) * 2048 + n) * 64 + d;
                    qh[idx] = hs;
                    ql[idx] = f2b(val - b2f(hs));
                } else if (mode == 1) {
                    kh[((size_t)(bb * 16 + h) * 2048 + n) * 64 + d] = hs;
                } else {
                    vth[((size_t)(bb * 16 + h) * 64 + d) * 2048 + n] = hs;
                }
            }
        }
    }
}

// ---------------------------------------------------------------------------
// 2-term GEMM, output projection (unchanged R11).
// ---------------------------------------------------------------------------
__global__ __launch_bounds__(256, 3) void gemm_out(
    const unsigned short* __restrict__ Ah, const unsigned short* __restrict__ Al,
    unsigned short* __restrict__ wsS,
    const float* __restrict__ bias_p, float* __restrict__ oout)
{
    __shared__ unsigned short Ash[128 * 64], Asl[128 * 64];
    __shared__ unsigned short Bsh[128 * 64];

    const unsigned short* Wh = wsS + OFF_WH + 3UL * 1048576;

    const int tid  = threadIdx.x;
    const int lane = tid & 63;
    const int lm   = lane & 15;
    const int quad = lane >> 4;
    const int w    = tid >> 6;
    const int wr   = w >> 1, wc = w & 1;

    const int row0 = blockIdx.y * 128;
    const int col0 = blockIdx.x * 128;

    const int srow = lane >> 3;
    const int soct = (lane & 7) ^ (srow & 7);

    f32x4 acc[4][4] = {};

    for (int k0 = 0; k0 < 1024; k0 += 64) {
        if (k0) __syncthreads();
        #pragma unroll
        for (int i = 0; i < 4; ++i) {
            const int rb = w * 32 + i * 8;
            gll16(&Ah[(size_t)(row0 + rb + srow) * 1024 + k0 + soct * 8],
                  &Ash[rb * 64]);
            gll16(&Al[(size_t)(row0 + rb + srow) * 1024 + k0 + soct * 8],
                  &Asl[rb * 64]);
            gll16(&Wh[(size_t)(col0 + rb + srow) * 1024 + k0 + soct * 8],
                  &Bsh[rb * 64]);
        }
        __syncthreads();
        #pragma unroll
        for (int ks = 0; ks < 2; ++ks) {
            bf16x8 afh[4], afl[4], bfh[4];
            #pragma unroll
            for (int mi = 0; mi < 4; ++mi) {
                afh[mi] = *(const bf16x8*)&Ash[sw8(wr * 64 + mi * 16 + lm, ks * 4 + quad)];
                afl[mi] = *(const bf16x8*)&Asl[sw8(wr * 64 + mi * 16 + lm, ks * 4 + quad)];
            }
            #pragma unroll
            for (int ni = 0; ni < 4; ++ni)
                bfh[ni] = *(const bf16x8*)&Bsh[sw8(wc * 64 + ni * 16 + lm, ks * 4 + quad)];
            #pragma unroll
            for (int mi = 0; mi < 4; ++mi) {
                #pragma unroll
                for (int ni = 0; ni < 4; ++ni) {
                    acc[mi][ni] = __builtin_amdgcn_mfma_f32_16x16x32_bf16(
                        afh[mi], bfh[ni], acc[mi][ni], 0, 0, 0);
                    acc[mi][ni] = __builtin_amdgcn_mfma_f32_16x16x32_bf16(
                        afl[mi], bfh[ni], acc[mi][ni], 0, 0, 0);
                }
            }
        }
    }

    #pragma unroll
    for (int ni = 0; ni < 4; ++ni) {
        const int f = col0 + wc * 64 + ni * 16 + lm;
        const float bvv = bias_p[f];
        #pragma unroll
        for (int mi = 0; mi < 4; ++mi) {
            #pragma unroll
            for (int j = 0; j < 4; ++j) {
                const int row = row0 + wr * 64 + mi * 16 + quad * 4 + j;
                oout[(size_t)row * 1024 + f] = acc[mi][ni][j] + bvv;
            }
        }
    }
}

// ---------------------------------------------------------------------------
// Flash attention, 128 q-rows/block (wave owns 32 = 2 strips), deferred
// softmax, async K/V dbuf (global_load_lds), one barrier per K-tile.
// K/V b128 frag reads reused across both strips -> LDS pipe relief.
// LDS 48KB; grid 512 = 2 blocks/CU; launch_bounds(256,2) -> no VGPR clamp.
// ---------------------------------------------------------------------------
__global__ __launch_bounds__(256, 2) void attn_fast(
    const unsigned short* __restrict__ wsS, const float* __restrict__ mask,
    unsigned short* __restrict__ ch, unsigned short* __restrict__ cl)
{
    __shared__ unsigned short Ksh[2][64 * 64];   // [buf][kcol][d] hi
    __shared__ unsigned short Vth[2][64 * 64];   // [buf][d][k]    hi
    __shared__ unsigned short Psh[4][32 * 64];   // per-wave [q][k] hi

    const int tid  = threadIdx.x;
    const int lane = tid & 63;
    const int lm   = lane & 15;
    const int quad = lane >> 4;
    const int w    = tid >> 6;

    const int q0 = blockIdx.x * 128;
    const int h  = blockIdx.y;
    const int b  = blockIdx.z;
    const int bh = b * 16 + h;

    const unsigned short* Qhg = wsS + OFF_QH  + (size_t)bh * 2048 * 64;
    const unsigned short* Qlg = wsS + OFF_QL  + (size_t)bh * 2048 * 64;
    const unsigned short* Khg = wsS + OFF_KH  + (size_t)bh * 2048 * 64;
    const unsigned short* Vhg = wsS + OFF_VTH + (size_t)bh * 64 * 2048;
    const float* Mg = mask + (size_t)b * 2048 * 2048;

    // Q frags in registers: 2 row-strips x 2 k-halves; scale pre-folded in q
    bf16x8 qfh[2][2], qfl[2][2];
    #pragma unroll
    for (int mi = 0; mi < 2; ++mi)
        #pragma unroll
        for (int ks = 0; ks < 2; ++ks) {
            const size_t qo = (size_t)(q0 + w * 32 + mi * 16 + lm) * 64 + ks * 32 + quad * 8;
            qfh[mi][ks] = *(const bf16x8*)&Qhg[qo];
            qfl[mi][ks] = *(const bf16x8*)&Qlg[qo];
        }

    const int srow = lane >> 3;
    const int soct = (lane & 7) ^ (srow & 7);

    // prologue: async-load tile 0 into buf 0
    #pragma unroll
    for (int i = 0; i < 2; ++i) {
        const int rb = w * 16 + i * 8;               // wave-uniform row base
        gll16(&Khg[(size_t)(rb + srow) * 64 + soct * 8],   &Ksh[0][rb * 64]);
        gll16(&Vhg[(size_t)(rb + srow) * 2048 + soct * 8], &Vth[0][rb * 64]);
    }

    f32x4 o[2][4] = {};
    float lsum[2][4] = {};
    const int qwbase = q0 + w * 32 + quad * 4;       // + mi*16 + j

    for (int t = 0; t < 32; ++t) {
        const int k0 = t * 64;
        const int p  = t & 1;

        __syncthreads();   // drains vmcnt -> tile t resident in buf p

        // async-issue tile t+1 into buf 1-p (lands before next barrier)
        if (t < 31) {
            #pragma unroll
            for (int i = 0; i < 2; ++i) {
                const int rb = w * 16 + i * 8;
                gll16(&Khg[(size_t)(k0 + 64 + rb + srow) * 64 + soct * 8],
                      &Ksh[1 - p][rb * 64]);
                gll16(&Vhg[(size_t)(rb + srow) * 2048 + k0 + 64 + soct * 8],
                      &Vth[1 - p][rb * 64]);
            }
        }

        // mask loads (issued early, consumed after QK)
        float mreg[2][4][4];
        #pragma unroll
        for (int mi = 0; mi < 2; ++mi)
            #pragma unroll
            for (int j = 0; j < 4; ++j)
                #pragma unroll
                for (int ni = 0; ni < 4; ++ni)
                    mreg[mi][j][ni] =
                        Mg[(size_t)(qwbase + mi * 16 + j) * 2048 + k0 + ni * 16 + lm];

        // S ~= (qh+ql) K_hi^T : K frags shared across both strips
        f32x4 s[2][4] = {};
        #pragma unroll
        for (int ks = 0; ks < 2; ++ks) {
            #pragma unroll
            for (int ni = 0; ni < 4; ++ni) {
                bf16x8 kh = *(const bf16x8*)&Ksh[p][sw8(ni * 16 + lm, ks * 4 + quad)];
                #pragma unroll
                for (int mi = 0; mi < 2; ++mi) {
                    s[mi][ni] = __builtin_amdgcn_mfma_f32_16x16x32_bf16(qfh[mi][ks], kh, s[mi][ni], 0, 0, 0);
                    s[mi][ni] = __builtin_amdgcn_mfma_f32_16x16x32_bf16(qfl[mi][ks], kh, s[mi][ni], 0, 0, 0);
                }
            }
        }

        // p = exp(s * mask); per-lane partial row-sums; P(hi) -> own-wave LDS
        #pragma unroll
        for (int mi = 0; mi < 2; ++mi)
            #pragma unroll
            for (int j = 0; j < 4; ++j) {
                #pragma unroll
                for (int ni = 0; ni < 4; ++ni) {
                    const float pv = __expf(s[mi][ni][j] * mreg[mi][j][ni]);
                    lsum[mi][j] += pv;
                    Psh[w][swe(mi * 16 + quad * 4 + j, ni * 16 + lm)] = f2b(pv);
                }
            }

        // O += P_hi @ V_hi : V frags shared across both strips
        #pragma unroll
        for (int ks = 0; ks < 2; ++ks) {
            bf16x8 ph[2];
            #pragma unroll
            for (int mi = 0; mi < 2; ++mi)
                ph[mi] = *(const bf16x8*)&Psh[w][sw8(mi * 16 + lm, ks * 4 + quad)];
            #pragma unroll
            for (int ni = 0; ni < 4; ++ni) {
                bf16x8 vh = *(const bf16x8*)&Vth[p][sw8(ni * 16 + lm, ks * 4 + quad)];
                #pragma unroll
                for (int mi = 0; mi < 2; ++mi)
                    o[mi][ni] = __builtin_amdgcn_mfma_f32_16x16x32_bf16(ph[mi], vh, o[mi][ni], 0, 0, 0);
            }
        }
    }

    // epilogue: one cross-lane row-sum reduction, normalize, split-store concat
    #pragma unroll
    for (int mi = 0; mi < 2; ++mi)
        #pragma unroll
        for (int j = 0; j < 4; ++j) {
            float ls = lsum[mi][j];
            ls += __shfl_xor(ls, 1);
            ls += __shfl_xor(ls, 2);
            ls += __shfl_xor(ls, 4);
            ls += __shfl_xor(ls, 8);
            const float inv = 1.0f / ls;
            const int q = qwbase + mi * 16 + j;
            #pragma unroll
            for (int ni = 0; ni < 4; ++ni) {
                const float val = o[mi][ni][j] * inv;
                const size_t idx = ((size_t)b * 2048 + q) * 1024 + h * 64 + ni * 16 + lm;
                const short hs = f2b(val);
                ch[idx] = hs;
                cl[idx] = f2b(val - b2f(hs));
            }
        }
}

extern "C" void kernel_launch(void* const* d_in, const int* in_sizes, int n_in,
                              void* d_out, int out_size, void* d_ws, size_t ws_size,
                              hipStream_t stream) {
    const float* x    = (const float*)d_in[0];
    const float* mask = (const float*)d_in[1];
    const float* Wq   = (const float*)d_in[2];
    const float* bq   = (const float*)d_in[3];
    const float* Wk   = (const float*)d_in[4];
    const float* bk   = (const float*)d_in[5];
    const float* Wv   = (const float*)d_in[6];
    const float* bv   = (const float*)d_in[7];
    const float* Wo   = (const float*)d_in[8];
    const float* bo   = (const float*)d_in[9];

    unsigned short* wsS = (unsigned short*)d_ws;

    // 1. pre-split: W -> hi (Wq/8); x -> hi+lo
    split_wx<<<8192, 256, 0, stream>>>(Wq, Wk, Wv, Wo, x,
        wsS + OFF_WH, wsS + OFF_XH, wsS + OFF_XL);

    // 2. Q/K/V projections, ONE 768-block launch (Q 2t; K,V 1t)
    gemm_qkv<<<dim3(8, 32, 3), 256, 0, stream>>>(wsS, bq, bk, bv);

    // 3. flash attention: 128-row blocks, 512 = 2 blocks/CU
    attn_fast<<<dim3(16, 16, 2), 256, 0, stream>>>(
        wsS, mask, wsS + OFF_CH, wsS + OFF_CL);

    // 4. output projection (2-term)
    gemm_out<<<dim3(8, 32), 256, 0, stream>>>(
        wsS + OFF_CH, wsS + OFF_CL, wsS, bo, (float*)d_out);
}

// Round 13
// 246.861 us; speedup vs baseline: 1.3165x; 1.0824x over previous
//
#include <hip/hip_runtime.h>
#include <hip/hip_bf16.h>
#include <math.h>

// B=2, N=2048, M=1024, H=16, DK=64. fp32 in/out.
// R13: ALL projection GEMMs 1-term (Q/K/V/out), by R8's measured symmetry
// (dropping the A-lo term is invisible at the bf16 rounding floor).
// QK stays 2-term (qh+ql capture the fp32 accumulator of the Q projection);
// PV 1-term. attn = R11's proven 64-row kernel (R12's 128-row reverted:
// occupancy loss cancelled the LDS relief). GEMM LDS 32KB -> 4 blocks/CU.
// 1/8 attention scale folded into Wq/bq.

typedef __attribute__((ext_vector_type(8))) short bf16x8;
typedef __attribute__((ext_vector_type(4))) float f32x4;

typedef __attribute__((address_space(1))) void gvoid;   // global
typedef __attribute__((address_space(3))) void lvoid;   // LDS

// async 16B/lane global->LDS copy: 64 lanes -> 1KB at wave-uniform lds base
__device__ __forceinline__ void gll16(const void* g, void* l) {
    __builtin_amdgcn_global_load_lds(
        (gvoid*)(unsigned long long)g,
        (lvoid*)(unsigned int)(unsigned long long)l,   // low 32b = LDS offset
        16, 0, 0);
}

__device__ __forceinline__ short f2b(float f) {
    union { __hip_bfloat16 h; short s; } u;
    u.h = __float2bfloat16(f);   // RNE
    return u.s;
}
__device__ __forceinline__ float b2f(short s) {
    union { short s; __hip_bfloat16 h; } u;
    u.s = s;
    return __bfloat162float(u.h);
}

// XOR-swizzled element offset inside a [rows][64]-bf16 tile (16B blocks).
__device__ __forceinline__ int sw8(int r, int k8) {       // k8 = octet 0..7
    return (r << 6) + ((k8 ^ (r & 7)) << 3);
}
__device__ __forceinline__ int swe(int r, int k) {        // element-level
    return (r << 6) + (((k >> 3) ^ (r & 7)) << 3) + (k & 7);
}

// workspace layout (SHORT offsets). Every plane = 4194304 shorts (8 MB).
#define PLANE   4194304UL
#define OFF_WH  (0UL * PLANE)    // [4][1024][1024] W hi; Wq pre-scaled 1/8
#define OFF_XH  (1UL * PLANE)    // [4096][1024] x hi
#define OFF_QH  (2UL * PLANE)    // [B,H,N,DK]
#define OFF_QL  (3UL * PLANE)
#define OFF_KH  (4UL * PLANE)    // hi only
#define OFF_VTH (5UL * PLANE)    // [B,H,DK,N] hi only
#define OFF_CH  (6UL * PLANE)    // [B,N,M] concat hi only

// ---------------------------------------------------------------------------
// Pre-split: W -> hi (Wq scaled by 1/8); x -> hi only.
// ---------------------------------------------------------------------------
__global__ __launch_bounds__(256) void split_wx(
    const float* __restrict__ Wq, const float* __restrict__ Wk,
    const float* __restrict__ Wv, const float* __restrict__ Wo,
    const float* __restrict__ x,
    unsigned short* __restrict__ wh, unsigned short* __restrict__ xh)
{
    const int i = blockIdx.x * 256 + threadIdx.x;   // float4 idx, 2097152 total
    if (i < 1048576) {                               // weights
        const float* src = (i < 262144) ? Wq : (i < 524288) ? Wk
                         : (i < 786432) ? Wv : Wo;
        const float sc = (i < 262144) ? 0.125f : 1.0f;   // fold attention scale
        const int local = i & 262143;
        float4 v = ((const float4*)src)[local];
        short4 h;
        h.x = f2b(v.x * sc); h.y = f2b(v.y * sc);
        h.z = f2b(v.z * sc); h.w = f2b(v.w * sc);
        ((short4*)(wh + (size_t)(i >> 18) * 1048576))[local] = h;
    } else {                                         // x: hi only
        const int local = i - 1048576;
        float4 v = ((const float4*)x)[local];
        short4 h;
        h.x = f2b(v.x); h.y = f2b(v.y); h.z = f2b(v.z); h.w = f2b(v.w);
        ((short4*)xh)[local] = h;
    }
}

// ---------------------------------------------------------------------------
// Unified 1-term QKV GEMM: ONE launch (8,32,3) = 768 blocks, 4 blocks/CU.
// z=0: Q = xh @ Wq^T -> hi/lo planes (lo captures fp32 accumulator);
// z=1: K -> hi; z=2: V^T -> hi [B,H,DK,N]. LDS 32KB, async staging.
// ---------------------------------------------------------------------------
__global__ __launch_bounds__(256, 4) void gemm_qkv(
    unsigned short* __restrict__ wsS,
    const float* __restrict__ bq, const float* __restrict__ bk,
    const float* __restrict__ bv)
{
    __shared__ unsigned short Ash[128 * 64];
    __shared__ unsigned short Bsh[128 * 64];

    const int mode = blockIdx.z;                     // 0 Q, 1 K, 2 V
    const unsigned short* Ah = wsS + OFF_XH;
    const unsigned short* Wh = wsS + OFF_WH + (size_t)mode * 1048576;

    const int tid  = threadIdx.x;
    const int lane = tid & 63;
    const int lm   = lane & 15;
    const int quad = lane >> 4;
    const int w    = tid >> 6;
    const int wr   = w >> 1, wc = w & 1;

    const int row0 = blockIdx.y * 128;
    const int col0 = blockIdx.x * 128;

    // staging source pattern: lane l -> row +(l>>3), octet (l&7)^((l>>3)&7)
    const int srow = lane >> 3;
    const int soct = (lane & 7) ^ (srow & 7);

    f32x4 acc[4][4] = {};

    for (int k0 = 0; k0 < 1024; k0 += 64) {
        if (k0) __syncthreads();
        #pragma unroll
        for (int i = 0; i < 4; ++i) {
            const int rb = w * 32 + i * 8;           // wave-uniform row base
            gll16(&Ah[(size_t)(row0 + rb + srow) * 1024 + k0 + soct * 8],
                  &Ash[rb * 64]);
            gll16(&Wh[(size_t)(col0 + rb + srow) * 1024 + k0 + soct * 8],
                  &Bsh[rb * 64]);
        }
        __syncthreads();
        #pragma unroll
        for (int ks = 0; ks < 2; ++ks) {
            bf16x8 afh[4], bfh[4];
            #pragma unroll
            for (int mi = 0; mi < 4; ++mi)
                afh[mi] = *(const bf16x8*)&Ash[sw8(wr * 64 + mi * 16 + lm, ks * 4 + quad)];
            #pragma unroll
            for (int ni = 0; ni < 4; ++ni)
                bfh[ni] = *(const bf16x8*)&Bsh[sw8(wc * 64 + ni * 16 + lm, ks * 4 + quad)];
            #pragma unroll
            for (int mi = 0; mi < 4; ++mi) {
                #pragma unroll
                for (int ni = 0; ni < 4; ++ni)
                    acc[mi][ni] = __builtin_amdgcn_mfma_f32_16x16x32_bf16(
                        afh[mi], bfh[ni], acc[mi][ni], 0, 0, 0);
            }
        }
    }

    unsigned short* qh  = wsS + OFF_QH;
    unsigned short* ql  = wsS + OFF_QL;
    unsigned short* kh  = wsS + OFF_KH;
    unsigned short* vth = wsS + OFF_VTH;
    const float* bias = (mode == 0) ? bq : (mode == 1) ? bk : bv;
    const float bscale = (mode == 0) ? 0.125f : 1.0f;

    // epilogue: C/D layout col=lane&15, row=quad*4+reg
    #pragma unroll
    for (int ni = 0; ni < 4; ++ni) {
        const int f = col0 + wc * 64 + ni * 16 + lm;
        const float bvv = bias[f] * bscale;
        const int h = f >> 6, d = f & 63;
        #pragma unroll
        for (int mi = 0; mi < 4; ++mi) {
            #pragma unroll
            for (int j = 0; j < 4; ++j) {
                const int row = row0 + wr * 64 + mi * 16 + quad * 4 + j;
                const float val = acc[mi][ni][j] + bvv;
                const int bb = row >> 11, n = row & 2047;
                const short hs = f2b(val);
                if (mode == 0) {
                    const size_t idx = ((size_t)(bb * 16 + h) * 2048 + n) * 64 + d;
                    qh[idx] = hs;
                    ql[idx] = f2b(val - b2f(hs));   // fp32-accumulator residue
                } else if (mode == 1) {
                    kh[((size_t)(bb * 16 + h) * 2048 + n) * 64 + d] = hs;
                } else {
                    vth[((size_t)(bb * 16 + h) * 64 + d) * 2048 + n] = hs;
                }
            }
        }
    }
}

// ---------------------------------------------------------------------------
// 1-term output projection: out = ch @ Wo^T + bo (fp32). LDS 32KB, 4 blk/CU.
// ---------------------------------------------------------------------------
__global__ __launch_bounds__(256, 4) void gemm_out(
    const unsigned short* __restrict__ Ah,
    unsigned short* __restrict__ wsS,
    const float* __restrict__ bias_p, float* __restrict__ oout)
{
    __shared__ unsigned short Ash[128 * 64];
    __shared__ unsigned short Bsh[128 * 64];

    const unsigned short* Wh = wsS + OFF_WH + 3UL * 1048576;

    const int tid  = threadIdx.x;
    const int lane = tid & 63;
    const int lm   = lane & 15;
    const int quad = lane >> 4;
    const int w    = tid >> 6;
    const int wr   = w >> 1, wc = w & 1;

    const int row0 = blockIdx.y * 128;
    const int col0 = blockIdx.x * 128;

    const int srow = lane >> 3;
    const int soct = (lane & 7) ^ (srow & 7);

    f32x4 acc[4][4] = {};

    for (int k0 = 0; k0 < 1024; k0 += 64) {
        if (k0) __syncthreads();
        #pragma unroll
        for (int i = 0; i < 4; ++i) {
            const int rb = w * 32 + i * 8;
            gll16(&Ah[(size_t)(row0 + rb + srow) * 1024 + k0 + soct * 8],
                  &Ash[rb * 64]);
            gll16(&Wh[(size_t)(col0 + rb + srow) * 1024 + k0 + soct * 8],
                  &Bsh[rb * 64]);
        }
        __syncthreads();
        #pragma unroll
        for (int ks = 0; ks < 2; ++ks) {
            bf16x8 afh[4], bfh[4];
            #pragma unroll
            for (int mi = 0; mi < 4; ++mi)
                afh[mi] = *(const bf16x8*)&Ash[sw8(wr * 64 + mi * 16 + lm, ks * 4 + quad)];
            #pragma unroll
            for (int ni = 0; ni < 4; ++ni)
                bfh[ni] = *(const bf16x8*)&Bsh[sw8(wc * 64 + ni * 16 + lm, ks * 4 + quad)];
            #pragma unroll
            for (int mi = 0; mi < 4; ++mi) {
                #pragma unroll
                for (int ni = 0; ni < 4; ++ni)
                    acc[mi][ni] = __builtin_amdgcn_mfma_f32_16x16x32_bf16(
                        afh[mi], bfh[ni], acc[mi][ni], 0, 0, 0);
            }
        }
    }

    #pragma unroll
    for (int ni = 0; ni < 4; ++ni) {
        const int f = col0 + wc * 64 + ni * 16 + lm;
        const float bvv = bias_p[f];
        #pragma unroll
        for (int mi = 0; mi < 4; ++mi) {
            #pragma unroll
            for (int j = 0; j < 4; ++j) {
                const int row = row0 + wr * 64 + mi * 16 + quad * 4 + j;
                oout[(size_t)row * 1024 + f] = acc[mi][ni][j] + bvv;
            }
        }
    }
}

// ---------------------------------------------------------------------------
// Flash attention (R11, proven): 64 q-rows/block, deferred softmax, async
// K/V dbuf (global_load_lds), one barrier per K-tile. QK 2-term, PV 1-term.
// LDS 40KB -> 4 blocks/CU. Output: concat hi plane only.
// ---------------------------------------------------------------------------
__global__ __launch_bounds__(256, 4) void attn_fast(
    const unsigned short* __restrict__ wsS, const float* __restrict__ mask,
    unsigned short* __restrict__ ch)
{
    __shared__ unsigned short Ksh[2][64 * 64];   // [buf][kcol][d] hi
    __shared__ unsigned short Vth[2][64 * 64];   // [buf][d][k]    hi
    __shared__ unsigned short Psh[4][16 * 64];   // per-wave [q][k] hi

    const int tid  = threadIdx.x;
    const int lane = tid & 63;
    const int lm   = lane & 15;
    const int quad = lane >> 4;
    const int w    = tid >> 6;

    const int q0 = blockIdx.x * 64;
    const int h  = blockIdx.y;
    const int b  = blockIdx.z;
    const int bh = b * 16 + h;

    const unsigned short* Qhg = wsS + OFF_QH  + (size_t)bh * 2048 * 64;
    const unsigned short* Qlg = wsS + OFF_QL  + (size_t)bh * 2048 * 64;
    const unsigned short* Khg = wsS + OFF_KH  + (size_t)bh * 2048 * 64;
    const unsigned short* Vhg = wsS + OFF_VTH + (size_t)bh * 64 * 2048;
    const float* Mg = mask + (size_t)b * 2048 * 2048;

    // Q frags in registers (this wave's 16 q-rows); scale pre-folded in q
    bf16x8 qfh[2], qfl[2];
    #pragma unroll
    for (int ks = 0; ks < 2; ++ks) {
        const size_t qo = (size_t)(q0 + w * 16 + lm) * 64 + ks * 32 + quad * 8;
        qfh[ks] = *(const bf16x8*)&Qhg[qo];
        qfl[ks] = *(const bf16x8*)&Qlg[qo];
    }

    const int srow = lane >> 3;
    const int soct = (lane & 7) ^ (srow & 7);

    // prologue: async-load tile 0 into buf 0
    #pragma unroll
    for (int i = 0; i < 2; ++i) {
        const int rb = w * 16 + i * 8;               // wave-uniform row base
        gll16(&Khg[(size_t)(rb + srow) * 64 + soct * 8],   &Ksh[0][rb * 64]);
        gll16(&Vhg[(size_t)(rb + srow) * 2048 + soct * 8], &Vth[0][rb * 64]);
    }

    f32x4 o[4] = {};
    float lsum[4] = {0.f, 0.f, 0.f, 0.f};
    const int qwbase = q0 + w * 16 + quad * 4;

    for (int t = 0; t < 32; ++t) {
        const int k0 = t * 64;
        const int p  = t & 1;

        __syncthreads();   // drains vmcnt -> tile t resident in buf p

        // async-issue tile t+1 into buf 1-p (lands before next barrier)
        if (t < 31) {
            #pragma unroll
            for (int i = 0; i < 2; ++i) {
                const int rb = w * 16 + i * 8;
                gll16(&Khg[(size_t)(k0 + 64 + rb + srow) * 64 + soct * 8],
                      &Ksh[1 - p][rb * 64]);
                gll16(&Vhg[(size_t)(rb + srow) * 2048 + k0 + 64 + soct * 8],
                      &Vth[1 - p][rb * 64]);
            }
        }

        float mreg[4][4];
        #pragma unroll
        for (int j = 0; j < 4; ++j)
            #pragma unroll
            for (int ni = 0; ni < 4; ++ni)
                mreg[j][ni] = Mg[(size_t)(qwbase + j) * 2048 + k0 + ni * 16 + lm];

        // S ~= (qh+ql) K_hi^T : 2 MFMA per (ks,ni)
        f32x4 s[4] = {};
        #pragma unroll
        for (int ks = 0; ks < 2; ++ks) {
            #pragma unroll
            for (int ni = 0; ni < 4; ++ni) {
                bf16x8 kh = *(const bf16x8*)&Ksh[p][sw8(ni * 16 + lm, ks * 4 + quad)];
                s[ni] = __builtin_amdgcn_mfma_f32_16x16x32_bf16(qfh[ks], kh, s[ni], 0, 0, 0);
                s[ni] = __builtin_amdgcn_mfma_f32_16x16x32_bf16(qfl[ks], kh, s[ni], 0, 0, 0);
            }
        }

        // p = exp(s * mask); per-lane partial row-sums; P(hi) -> own-wave LDS
        #pragma unroll
        for (int j = 0; j < 4; ++j) {
            #pragma unroll
            for (int ni = 0; ni < 4; ++ni) {
                const float pv = __expf(s[ni][j] * mreg[j][ni]);
                lsum[j] += pv;
                Psh[w][swe(quad * 4 + j, ni * 16 + lm)] = f2b(pv);
            }
        }

        // O += P_hi @ V_hi : 1 MFMA per (ks,ni)
        #pragma unroll
        for (int ks = 0; ks < 2; ++ks) {
            bf16x8 ph = *(const bf16x8*)&Psh[w][sw8(lm, ks * 4 + quad)];
            #pragma unroll
            for (int ni = 0; ni < 4; ++ni) {
                bf16x8 vh = *(const bf16x8*)&Vth[p][sw8(ni * 16 + lm, ks * 4 + quad)];
                o[ni] = __builtin_amdgcn_mfma_f32_16x16x32_bf16(ph, vh, o[ni], 0, 0, 0);
            }
        }
    }

    // epilogue: one cross-lane row-sum reduction, normalize, store concat hi
    #pragma unroll
    for (int j = 0; j < 4; ++j) {
        float ls = lsum[j];
        ls += __shfl_xor(ls, 1);
        ls += __shfl_xor(ls, 2);
        ls += __shfl_xor(ls, 4);
        ls += __shfl_xor(ls, 8);
        const float inv = 1.0f / ls;
        const int q = qwbase + j;
        #pragma unroll
        for (int ni = 0; ni < 4; ++ni)
            ch[((size_t)b * 2048 + q) * 1024 + h * 64 + ni * 16 + lm] =
                (unsigned short)f2b(o[ni][j] * inv);
    }
}

extern "C" void kernel_launch(void* const* d_in, const int* in_sizes, int n_in,
                              void* d_out, int out_size, void* d_ws, size_t ws_size,
                              hipStream_t stream) {
    const float* x    = (const float*)d_in[0];
    const float* mask = (const float*)d_in[1];
    const float* Wq   = (const float*)d_in[2];
    const float* bq   = (const float*)d_in[3];
    const float* Wk   = (const float*)d_in[4];
    const float* bk   = (const float*)d_in[5];
    const float* Wv   = (const float*)d_in[6];
    const float* bv   = (const float*)d_in[7];
    const float* Wo   = (const float*)d_in[8];
    const float* bo   = (const float*)d_in[9];

    unsigned short* wsS = (unsigned short*)d_ws;

    // 1. pre-split: W -> hi (Wq/8); x -> hi
    split_wx<<<8192, 256, 0, stream>>>(Wq, Wk, Wv, Wo, x,
        wsS + OFF_WH, wsS + OFF_XH);

    // 2. Q/K/V projections, ONE 768-block launch, all 1-term, 4 blocks/CU
    gemm_qkv<<<dim3(8, 32, 3), 256, 0, stream>>>(wsS, bq, bk, bv);

    // 3. flash attention (R11 64-row, QK 2t / PV 1t)
    attn_fast<<<dim3(32, 16, 2), 256, 0, stream>>>(wsS, mask, wsS + OFF_CH);

    // 4. output projection (1-term)
    gemm_out<<<dim3(8, 32), 256, 0, stream>>>(
        wsS + OFF_CH, wsS, bo, (float*)d_out);
}

// Round 14
// 244.443 us; speedup vs baseline: 1.3295x; 1.0099x over previous
//
#include <hip/hip_runtime.h>
#include <hip/hip_bf16.h>
#include <math.h>

// B=2, N=2048, M=1024, H=16, DK=64. fp32 in/out.
// R14 = R13 + gemm_out at 512 threads (8 waves, 2x4 layout, same 128x128
// tile): R13's out-GEMM ran 256 blocks = 1 block/CU x 4 waves — the exact
// no-TLP configuration R9 proved bad. 8 waves/CU doubles latency hiding.
// Precision plan (absmax 9.77e-4, stable since R7):
//   all projections 1-term | QK 2-term (ql = fp32-accumulator residue) | PV 1t
// 1/8 attention scale folded into Wq/bq.

typedef __attribute__((ext_vector_type(8))) short bf16x8;
typedef __attribute__((ext_vector_type(4))) float f32x4;

typedef __attribute__((address_space(1))) void gvoid;   // global
typedef __attribute__((address_space(3))) void lvoid;   // LDS

// async 16B/lane global->LDS copy: 64 lanes -> 1KB at wave-uniform lds base
__device__ __forceinline__ void gll16(const void* g, void* l) {
    __builtin_amdgcn_global_load_lds(
        (gvoid*)(unsigned long long)g,
        (lvoid*)(unsigned int)(unsigned long long)l,   // low 32b = LDS offset
        16, 0, 0);
}

__device__ __forceinline__ short f2b(float f) {
    union { __hip_bfloat16 h; short s; } u;
    u.h = __float2bfloat16(f);   // RNE
    return u.s;
}
__device__ __forceinline__ float b2f(short s) {
    union { short s; __hip_bfloat16 h; } u;
    u.s = s;
    return __bfloat162float(u.h);
}

// XOR-swizzled element offset inside a [rows][64]-bf16 tile (16B blocks).
__device__ __forceinline__ int sw8(int r, int k8) {       // k8 = octet 0..7
    return (r << 6) + ((k8 ^ (r & 7)) << 3);
}
__device__ __forceinline__ int swe(int r, int k) {        // element-level
    return (r << 6) + (((k >> 3) ^ (r & 7)) << 3) + (k & 7);
}

// workspace layout (SHORT offsets). Every plane = 4194304 shorts (8 MB).
#define PLANE   4194304UL
#define OFF_WH  (0UL * PLANE)    // [4][1024][1024] W hi; Wq pre-scaled 1/8
#define OFF_XH  (1UL * PLANE)    // [4096][1024] x hi
#define OFF_QH  (2UL * PLANE)    // [B,H,N,DK]
#define OFF_QL  (3UL * PLANE)
#define OFF_KH  (4UL * PLANE)    // hi only
#define OFF_VTH (5UL * PLANE)    // [B,H,DK,N] hi only
#define OFF_CH  (6UL * PLANE)    // [B,N,M] concat hi only

// ---------------------------------------------------------------------------
// Pre-split: W -> hi (Wq scaled by 1/8); x -> hi only.
// ---------------------------------------------------------------------------
__global__ __launch_bounds__(256) void split_wx(
    const float* __restrict__ Wq, const float* __restrict__ Wk,
    const float* __restrict__ Wv, const float* __restrict__ Wo,
    const float* __restrict__ x,
    unsigned short* __restrict__ wh, unsigned short* __restrict__ xh)
{
    const int i = blockIdx.x * 256 + threadIdx.x;   // float4 idx, 2097152 total
    if (i < 1048576) {                               // weights
        const float* src = (i < 262144) ? Wq : (i < 524288) ? Wk
                         : (i < 786432) ? Wv : Wo;
        const float sc = (i < 262144) ? 0.125f : 1.0f;   // fold attention scale
        const int local = i & 262143;
        float4 v = ((const float4*)src)[local];
        short4 h;
        h.x = f2b(v.x * sc); h.y = f2b(v.y * sc);
        h.z = f2b(v.z * sc); h.w = f2b(v.w * sc);
        ((short4*)(wh + (size_t)(i >> 18) * 1048576))[local] = h;
    } else {                                         // x: hi only
        const int local = i - 1048576;
        float4 v = ((const float4*)x)[local];
        short4 h;
        h.x = f2b(v.x); h.y = f2b(v.y); h.z = f2b(v.z); h.w = f2b(v.w);
        ((short4*)xh)[local] = h;
    }
}

// ---------------------------------------------------------------------------
// Unified 1-term QKV GEMM (R13): ONE launch (8,32,3) = 768 blocks, LDS 32KB.
// z=0: Q -> hi/lo planes (lo = fp32-accumulator residue); z=1: K; z=2: V^T.
// ---------------------------------------------------------------------------
__global__ __launch_bounds__(256, 4) void gemm_qkv(
    unsigned short* __restrict__ wsS,
    const float* __restrict__ bq, const float* __restrict__ bk,
    const float* __restrict__ bv)
{
    __shared__ unsigned short Ash[128 * 64];
    __shared__ unsigned short Bsh[128 * 64];

    const int mode = blockIdx.z;                     // 0 Q, 1 K, 2 V
    const unsigned short* Ah = wsS + OFF_XH;
    const unsigned short* Wh = wsS + OFF_WH + (size_t)mode * 1048576;

    const int tid  = threadIdx.x;
    const int lane = tid & 63;
    const int lm   = lane & 15;
    const int quad = lane >> 4;
    const int w    = tid >> 6;
    const int wr   = w >> 1, wc = w & 1;

    const int row0 = blockIdx.y * 128;
    const int col0 = blockIdx.x * 128;

    const int srow = lane >> 3;
    const int soct = (lane & 7) ^ (srow & 7);

    f32x4 acc[4][4] = {};

    for (int k0 = 0; k0 < 1024; k0 += 64) {
        if (k0) __syncthreads();
        #pragma unroll
        for (int i = 0; i < 4; ++i) {
            const int rb = w * 32 + i * 8;           // wave-uniform row base
            gll16(&Ah[(size_t)(row0 + rb + srow) * 1024 + k0 + soct * 8],
                  &Ash[rb * 64]);
            gll16(&Wh[(size_t)(col0 + rb + srow) * 1024 + k0 + soct * 8],
                  &Bsh[rb * 64]);
        }
        __syncthreads();
        #pragma unroll
        for (int ks = 0; ks < 2; ++ks) {
            bf16x8 afh[4], bfh[4];
            #pragma unroll
            for (int mi = 0; mi < 4; ++mi)
                afh[mi] = *(const bf16x8*)&Ash[sw8(wr * 64 + mi * 16 + lm, ks * 4 + quad)];
            #pragma unroll
            for (int ni = 0; ni < 4; ++ni)
                bfh[ni] = *(const bf16x8*)&Bsh[sw8(wc * 64 + ni * 16 + lm, ks * 4 + quad)];
            #pragma unroll
            for (int mi = 0; mi < 4; ++mi) {
                #pragma unroll
                for (int ni = 0; ni < 4; ++ni)
                    acc[mi][ni] = __builtin_amdgcn_mfma_f32_16x16x32_bf16(
                        afh[mi], bfh[ni], acc[mi][ni], 0, 0, 0);
            }
        }
    }

    unsigned short* qh  = wsS + OFF_QH;
    unsigned short* ql  = wsS + OFF_QL;
    unsigned short* kh  = wsS + OFF_KH;
    unsigned short* vth = wsS + OFF_VTH;
    const float* bias = (mode == 0) ? bq : (mode == 1) ? bk : bv;
    const float bscale = (mode == 0) ? 0.125f : 1.0f;

    #pragma unroll
    for (int ni = 0; ni < 4; ++ni) {
        const int f = col0 + wc * 64 + ni * 16 + lm;
        const float bvv = bias[f] * bscale;
        const int h = f >> 6, d = f & 63;
        #pragma unroll
        for (int mi = 0; mi < 4; ++mi) {
            #pragma unroll
            for (int j = 0; j < 4; ++j) {
                const int row = row0 + wr * 64 + mi * 16 + quad * 4 + j;
                const float val = acc[mi][ni][j] + bvv;
                const int bb = row >> 11, n = row & 2047;
                const short hs = f2b(val);
                if (mode == 0) {
                    const size_t idx = ((size_t)(bb * 16 + h) * 2048 + n) * 64 + d;
                    qh[idx] = hs;
                    ql[idx] = f2b(val - b2f(hs));   // fp32-accumulator residue
                } else if (mode == 1) {
                    kh[((size_t)(bb * 16 + h) * 2048 + n) * 64 + d] = hs;
                } else {
                    vth[((size_t)(bb * 16 + h) * 64 + d) * 2048 + n] = hs;
                }
            }
        }
    }
}

// ---------------------------------------------------------------------------
// 1-term output projection, 512 threads / 8 waves (2 row-halves x 4 col-
// quarters): out = ch @ Wo^T + bo (fp32). Same 128x128 tile and LDS 32KB;
// 8 waves/CU instead of R13's 4 -> latency hiding doubled at 1 block/CU.
// ---------------------------------------------------------------------------
__global__ __launch_bounds__(512, 2) void gemm_out(
    const unsigned short* __restrict__ Ah,
    unsigned short* __restrict__ wsS,
    const float* __restrict__ bias_p, float* __restrict__ oout)
{
    __shared__ unsigned short Ash[128 * 64];
    __shared__ unsigned short Bsh[128 * 64];

    const unsigned short* Wh = wsS + OFF_WH + 3UL * 1048576;

    const int tid  = threadIdx.x;
    const int lane = tid & 63;
    const int lm   = lane & 15;
    const int quad = lane >> 4;
    const int w    = tid >> 6;          // 0..7
    const int wr   = w >> 2;            // 0..1  (64-row half)
    const int wc   = w & 3;             // 0..3  (32-col quarter)

    const int row0 = blockIdx.y * 128;
    const int col0 = blockIdx.x * 128;

    const int srow = lane >> 3;
    const int soct = (lane & 7) ^ (srow & 7);

    f32x4 acc[4][2] = {};

    for (int k0 = 0; k0 < 1024; k0 += 64) {
        if (k0) __syncthreads();
        #pragma unroll
        for (int i = 0; i < 2; ++i) {           // 8 waves x 2 x 1KB = 16KB each
            const int rb = w * 16 + i * 8;
            gll16(&Ah[(size_t)(row0 + rb + srow) * 1024 + k0 + soct * 8],
                  &Ash[rb * 64]);
            gll16(&Wh[(size_t)(col0 + rb + srow) * 1024 + k0 + soct * 8],
                  &Bsh[rb * 64]);
        }
        __syncthreads();
        #pragma unroll
        for (int ks = 0; ks < 2; ++ks) {
            bf16x8 afh[4], bfh[2];
            #pragma unroll
            for (int mi = 0; mi < 4; ++mi)
                afh[mi] = *(const bf16x8*)&Ash[sw8(wr * 64 + mi * 16 + lm, ks * 4 + quad)];
            #pragma unroll
            for (int ni = 0; ni < 2; ++ni)
                bfh[ni] = *(const bf16x8*)&Bsh[sw8(wc * 32 + ni * 16 + lm, ks * 4 + quad)];
            #pragma unroll
            for (int mi = 0; mi < 4; ++mi) {
                #pragma unroll
                for (int ni = 0; ni < 2; ++ni)
                    acc[mi][ni] = __builtin_amdgcn_mfma_f32_16x16x32_bf16(
                        afh[mi], bfh[ni], acc[mi][ni], 0, 0, 0);
            }
        }
    }

    #pragma unroll
    for (int ni = 0; ni < 2; ++ni) {
        const int f = col0 + wc * 32 + ni * 16 + lm;
        const float bvv = bias_p[f];
        #pragma unroll
        for (int mi = 0; mi < 4; ++mi) {
            #pragma unroll
            for (int j = 0; j < 4; ++j) {
                const int row = row0 + wr * 64 + mi * 16 + quad * 4 + j;
                oout[(size_t)row * 1024 + f] = acc[mi][ni][j] + bvv;
            }
        }
    }
}

// ---------------------------------------------------------------------------
// Flash attention (R11/R13, proven): 64 q-rows/block, deferred softmax,
// async K/V dbuf, one barrier per K-tile. QK 2-term, PV 1-term. LDS 40KB.
// ---------------------------------------------------------------------------
__global__ __launch_bounds__(256, 4) void attn_fast(
    const unsigned short* __restrict__ wsS, const float* __restrict__ mask,
    unsigned short* __restrict__ ch)
{
    __shared__ unsigned short Ksh[2][64 * 64];   // [buf][kcol][d] hi
    __shared__ unsigned short Vth[2][64 * 64];   // [buf][d][k]    hi
    __shared__ unsigned short Psh[4][16 * 64];   // per-wave [q][k] hi

    const int tid  = threadIdx.x;
    const int lane = tid & 63;
    const int lm   = lane & 15;
    const int quad = lane >> 4;
    const int w    = tid >> 6;

    const int q0 = blockIdx.x * 64;
    const int h  = blockIdx.y;
    const int b  = blockIdx.z;
    const int bh = b * 16 + h;

    const unsigned short* Qhg = wsS + OFF_QH  + (size_t)bh * 2048 * 64;
    const unsigned short* Qlg = wsS + OFF_QL  + (size_t)bh * 2048 * 64;
    const unsigned short* Khg = wsS + OFF_KH  + (size_t)bh * 2048 * 64;
    const unsigned short* Vhg = wsS + OFF_VTH + (size_t)bh * 64 * 2048;
    const float* Mg = mask + (size_t)b * 2048 * 2048;

    // Q frags in registers (this wave's 16 q-rows); scale pre-folded in q
    bf16x8 qfh[2], qfl[2];
    #pragma unroll
    for (int ks = 0; ks < 2; ++ks) {
        const size_t qo = (size_t)(q0 + w * 16 + lm) * 64 + ks * 32 + quad * 8;
        qfh[ks] = *(const bf16x8*)&Qhg[qo];
        qfl[ks] = *(const bf16x8*)&Qlg[qo];
    }

    const int srow = lane >> 3;
    const int soct = (lane & 7) ^ (srow & 7);

    // prologue: async-load tile 0 into buf 0
    #pragma unroll
    for (int i = 0; i < 2; ++i) {
        const int rb = w * 16 + i * 8;               // wave-uniform row base
        gll16(&Khg[(size_t)(rb + srow) * 64 + soct * 8],   &Ksh[0][rb * 64]);
        gll16(&Vhg[(size_t)(rb + srow) * 2048 + soct * 8], &Vth[0][rb * 64]);
    }

    f32x4 o[4] = {};
    float lsum[4] = {0.f, 0.f, 0.f, 0.f};
    const int qwbase = q0 + w * 16 + quad * 4;

    for (int t = 0; t < 32; ++t) {
        const int k0 = t * 64;
        const int p  = t & 1;

        __syncthreads();   // drains vmcnt -> tile t resident in buf p

        // async-issue tile t+1 into buf 1-p (lands before next barrier)
        if (t < 31) {
            #pragma unroll
            for (int i = 0; i < 2; ++i) {
                const int rb = w * 16 + i * 8;
                gll16(&Khg[(size_t)(k0 + 64 + rb + srow) * 64 + soct * 8],
                      &Ksh[1 - p][rb * 64]);
                gll16(&Vhg[(size_t)(rb + srow) * 2048 + k0 + 64 + soct * 8],
                      &Vth[1 - p][rb * 64]);
            }
        }

        float mreg[4][4];
        #pragma unroll
        for (int j = 0; j < 4; ++j)
            #pragma unroll
            for (int ni = 0; ni < 4; ++ni)
                mreg[j][ni] = Mg[(size_t)(qwbase + j) * 2048 + k0 + ni * 16 + lm];

        // S ~= (qh+ql) K_hi^T : 2 MFMA per (ks,ni)
        f32x4 s[4] = {};
        #pragma unroll
        for (int ks = 0; ks < 2; ++ks) {
            #pragma unroll
            for (int ni = 0; ni < 4; ++ni) {
                bf16x8 kh = *(const bf16x8*)&Ksh[p][sw8(ni * 16 + lm, ks * 4 + quad)];
                s[ni] = __builtin_amdgcn_mfma_f32_16x16x32_bf16(qfh[ks], kh, s[ni], 0, 0, 0);
                s[ni] = __builtin_amdgcn_mfma_f32_16x16x32_bf16(qfl[ks], kh, s[ni], 0, 0, 0);
            }
        }

        // p = exp(s * mask); per-lane partial row-sums; P(hi) -> own-wave LDS
        #pragma unroll
        for (int j = 0; j < 4; ++j) {
            #pragma unroll
            for (int ni = 0; ni < 4; ++ni) {
                const float pv = __expf(s[ni][j] * mreg[j][ni]);
                lsum[j] += pv;
                Psh[w][swe(quad * 4 + j, ni * 16 + lm)] = f2b(pv);
            }
        }

        // O += P_hi @ V_hi : 1 MFMA per (ks,ni)
        #pragma unroll
        for (int ks = 0; ks < 2; ++ks) {
            bf16x8 ph = *(const bf16x8*)&Psh[w][sw8(lm, ks * 4 + quad)];
            #pragma unroll
            for (int ni = 0; ni < 4; ++ni) {
                bf16x8 vh = *(const bf16x8*)&Vth[p][sw8(ni * 16 + lm, ks * 4 + quad)];
                o[ni] = __builtin_amdgcn_mfma_f32_16x16x32_bf16(ph, vh, o[ni], 0, 0, 0);
            }
        }
    }

    // epilogue: one cross-lane row-sum reduction, normalize, store concat hi
    #pragma unroll
    for (int j = 0; j < 4; ++j) {
        float ls = lsum[j];
        ls += __shfl_xor(ls, 1);
        ls += __shfl_xor(ls, 2);
        ls += __shfl_xor(ls, 4);
        ls += __shfl_xor(ls, 8);
        const float inv = 1.0f / ls;
        const int q = qwbase + j;
        #pragma unroll
        for (int ni = 0; ni < 4; ++ni)
            ch[((size_t)b * 2048 + q) * 1024 + h * 64 + ni * 16 + lm] =
                (unsigned short)f2b(o[ni][j] * inv);
    }
}

extern "C" void kernel_launch(void* const* d_in, const int* in_sizes, int n_in,
                              void* d_out, int out_size, void* d_ws, size_t ws_size,
                              hipStream_t stream) {
    const float* x    = (const float*)d_in[0];
    const float* mask = (const float*)d_in[1];
    const float* Wq   = (const float*)d_in[2];
    const float* bq   = (const float*)d_in[3];
    const float* Wk   = (const float*)d_in[4];
    const float* bk   = (const float*)d_in[5];
    const float* Wv   = (const float*)d_in[6];
    const float* bv   = (const float*)d_in[7];
    const float* Wo   = (const float*)d_in[8];
    const float* bo   = (const float*)d_in[9];

    unsigned short* wsS = (unsigned short*)d_ws;

    // 1. pre-split: W -> hi (Wq/8); x -> hi
    split_wx<<<8192, 256, 0, stream>>>(Wq, Wk, Wv, Wo, x,
        wsS + OFF_WH, wsS + OFF_XH);

    // 2. Q/K/V projections, ONE 768-block launch, all 1-term
    gemm_qkv<<<dim3(8, 32, 3), 256, 0, stream>>>(wsS, bq, bk, bv);

    // 3. flash attention (64-row, QK 2t / PV 1t)
    attn_fast<<<dim3(32, 16, 2), 256, 0, stream>>>(wsS, mask, wsS + OFF_CH);

    // 4. output projection: 512 threads, 8 waves/CU
    gemm_out<<<dim3(8, 32), 512, 0, stream>>>(
        wsS + OFF_CH, wsS, bo, (float*)d_out);
}